// Round 6
// baseline (584.605 us; speedup 1.0000x reference)
//
#include <hip/hip_runtime.h>
#include <hip/hip_fp16.h>

#define HIDDEN 128

// ---------------------------------------------------------------- degree count
__global__ __launch_bounds__(256) void count_kernel(const int* __restrict__ col,
                                                    int* __restrict__ deg, int E) {
    int e = blockIdx.x * 256 + threadIdx.x;
    if (e < E) atomicAdd(&deg[col[e]], 1);
}

// ----------------------------------------------------- scan phase 1: block sums
__global__ __launch_bounds__(256) void scan_blocksums(const int* __restrict__ deg,
                                                      int* __restrict__ bsums, int N) {
    __shared__ int red[256];
    int t = threadIdx.x;
    int base = blockIdx.x * 1024 + t * 4;
    int s = 0;
    if (base + 3 < N) {
        int4 v = *(const int4*)(deg + base);
        s = v.x + v.y + v.z + v.w;
    } else {
        for (int k = 0; k < 4; ++k) if (base + k < N) s += deg[base + k];
    }
    red[t] = s;
    __syncthreads();
    for (int d = 128; d > 0; d >>= 1) {
        if (t < d) red[t] += red[t + d];
        __syncthreads();
    }
    if (t == 0) bsums[blockIdx.x] = red[0];
}

// ------------------------------------- scan phase 2: write offsets/cursor/dinv
__global__ __launch_bounds__(256) void scan_write(const int* __restrict__ deg,
                                                  const int* __restrict__ bsums,
                                                  int* __restrict__ offsets,
                                                  int* __restrict__ cursor,
                                                  float* __restrict__ dinv,
                                                  int N, int E) {
    __shared__ int incl[256];
    __shared__ int red[256];
    __shared__ int s_boff;
    int t = threadIdx.x;
    int base = blockIdx.x * 1024 + t * 4;
    int d0 = 0, d1 = 0, d2 = 0, d3 = 0;
    if (base + 3 < N) {
        int4 v = *(const int4*)(deg + base);
        d0 = v.x; d1 = v.y; d2 = v.z; d3 = v.w;
    } else {
        if (base + 0 < N) d0 = deg[base + 0];
        if (base + 1 < N) d1 = deg[base + 1];
        if (base + 2 < N) d2 = deg[base + 2];
        if (base + 3 < N) d3 = deg[base + 3];
    }
    int mysum = d0 + d1 + d2 + d3;
    incl[t] = mysum;
    int b = 0;
    for (int i = t; i < blockIdx.x; i += 256) b += bsums[i];
    red[t] = b;
    __syncthreads();
    for (int d = 128; d > 0; d >>= 1) {
        if (t < d) red[t] += red[t + d];
        __syncthreads();
    }
    if (t == 0) s_boff = red[0];
    for (int d = 1; d < 256; d <<= 1) {
        int v = (t >= d) ? incl[t - d] : 0;
        __syncthreads();
        incl[t] += v;
        __syncthreads();
    }
    int run = s_boff + incl[t] - mysum;
    if (base + 0 < N) { offsets[base + 0] = run; cursor[base + 0] = run; dinv[base + 0] = rsqrtf((float)(d0 + 1)); run += d0; }
    if (base + 1 < N) { offsets[base + 1] = run; cursor[base + 1] = run; dinv[base + 1] = rsqrtf((float)(d1 + 1)); run += d1; }
    if (base + 2 < N) { offsets[base + 2] = run; cursor[base + 2] = run; dinv[base + 2] = rsqrtf((float)(d2 + 1)); run += d2; }
    if (base + 3 < N) { offsets[base + 3] = run; cursor[base + 3] = run; dinv[base + 3] = rsqrtf((float)(d3 + 1)); run += d3; }
    if (blockIdx.x == 0 && t == 0) offsets[N] = E;
}

// --------------------------- CSR fill: 4-byte entries (source index only)
__global__ __launch_bounds__(256) void fill_kernel(const int* __restrict__ row,
                                                   const int* __restrict__ col,
                                                   int* __restrict__ cursor,
                                                   int* __restrict__ sorted_r, int E) {
    int e = blockIdx.x * 256 + threadIdx.x;
    if (e < E) {
        int c = col[e];
        int r = row[e];
        int p = atomicAdd(&cursor[c], 1);
        __builtin_nontemporal_store(r, &sorted_r[p]);
    }
}

// ----------------- pad x [N,11] -> fp16 [N,16], folding dinv[i] into the row
__global__ __launch_bounds__(256) void pad_x(const float* __restrict__ x,
                                             const float* __restrict__ dinv,
                                             __half* __restrict__ xp, int N) {
    int q = blockIdx.x * 256 + threadIdx.x;
    if (q >= N * 16) return;
    int i = q >> 4, c = q & 15;
    float v = (c < 11) ? x[(size_t)i * 11 + c] * dinv[i] : 0.f;
    xp[q] = __float2half(v);
}

// -------------------- aggregate 16-ch dinv-folded input: aggx[c]=dc*(sum+self)
// 8 edge-groups per wave, each lane loads half2 (2 channels)
__global__ __launch_bounds__(256) void agg16(const __half* __restrict__ xp,
                                             float* __restrict__ aggx,
                                             const int* __restrict__ offsets,
                                             const int* __restrict__ sorted_r,
                                             const float* __restrict__ dinv, int N) {
    int wid  = (blockIdx.x * 256 + threadIdx.x) >> 6;
    int lane = threadIdx.x & 63;
    if (wid >= N) return;
    int c = wid;
    int g = lane >> 3, cp = lane & 7;
    int beg = offsets[c], end = offsets[c + 1];
    const __half2* xp2 = (const __half2*)xp;
    float ax = 0.f, ay = 0.f;
    if (g == 0) {
        float2 v = __half22float2(xp2[(size_t)c * 8 + cp]);   // self (dc folded)
        ax = v.x; ay = v.y;
    }
    for (int idx = beg + g; idx < end; idx += 8) {
        int r = sorted_r[idx];
        float2 v = __half22float2(xp2[(size_t)r * 8 + cp]);
        ax += v.x; ay += v.y;
    }
    ax += __shfl_xor(ax, 32); ay += __shfl_xor(ay, 32);
    ax += __shfl_xor(ax, 16); ay += __shfl_xor(ay, 16);
    ax += __shfl_xor(ax, 8);  ay += __shfl_xor(ay, 8);
    if (lane < 8) {
        float dc = dinv[c];
        aggx[(size_t)c * 16 + cp * 2]     = ax * dc;
        aggx[(size_t)c * 16 + cp * 2 + 1] = ay * dc;
    }
}

// ---------------------------- GEMM: h1 = aggx[:, :11] @ W1 -> fp16 (conv1 out)
__global__ __launch_bounds__(256) void gemm_in_agg(const float* __restrict__ aggx,
                                                   const float* __restrict__ W1,
                                                   __half* __restrict__ out, int N) {
    int i = blockIdx.x * 2 + (threadIdx.x >> 7);
    int j = threadIdx.x & 127;
    if (i >= N) return;
    float acc = 0.f;
#pragma unroll
    for (int c = 0; c < 11; ++c) acc += aggx[(size_t)i * 16 + c] * W1[c * HIDDEN + j];
    out[(size_t)i * HIDDEN + j] = __float2half(acc);
}

// ------- GEMM: out_fp16 = dinv[i] * ( relu(H_fp16 + b) @ W )  (fp32 accumulate)
__global__ __launch_bounds__(256) void gemm128h(const __half* __restrict__ H,
                                                const float* __restrict__ bias,
                                                const float* __restrict__ W,
                                                const float* __restrict__ dinv,
                                                __half* __restrict__ out, int N) {
    __shared__ float Hlds[16][HIDDEN];   // 8 KB
    int t = threadIdx.x;
    int rowbase = blockIdx.x * 16;
    const __half2* H2 = (const __half2*)H;
    for (int q = t; q < 16 * 64; q += 256) {
        int r = q >> 6, kp = q & 63;
        int gr = rowbase + r;
        float2 v = make_float2(0.f, 0.f);
        if (gr < N) v = __half22float2(H2[(size_t)gr * 64 + kp]);
        Hlds[r][kp * 2]     = fmaxf(v.x + bias[kp * 2], 0.f);
        Hlds[r][kp * 2 + 1] = fmaxf(v.y + bias[kp * 2 + 1], 0.f);
    }
    __syncthreads();
    int j  = t & 127;
    int rb = t >> 7;
    float acc[8] = {0.f, 0.f, 0.f, 0.f, 0.f, 0.f, 0.f, 0.f};
#pragma unroll 4
    for (int k = 0; k < HIDDEN; ++k) {
        float wv = W[k * HIDDEN + j];
#pragma unroll
        for (int m = 0; m < 8; ++m) acc[m] += Hlds[rb + 2 * m][k] * wv;
    }
#pragma unroll
    for (int m = 0; m < 8; ++m) {
        int gr = rowbase + rb + 2 * m;
        if (gr < N) out[(size_t)gr * HIDDEN + j] = __float2half(acc[m] * dinv[gr]);
    }
}

// -------- aggregation 128ch fp16, no edge weights (dinv folded into features)
// dst[c] = fp16( dc * (sum_r src[r] + src[c]) ); 16 lanes/edge, 4 groups, x4 unroll
__global__ __launch_bounds__(256) void agg128h(const __half* __restrict__ src,
                                               __half* __restrict__ dst,
                                               const int* __restrict__ offsets,
                                               const int* __restrict__ sorted_r,
                                               const float* __restrict__ dinv, int N) {
    int wid  = (blockIdx.x * 256 + threadIdx.x) >> 6;
    int lane = threadIdx.x & 63;
    if (wid >= N) return;
    int c = wid;
    int beg = offsets[c], end = offsets[c + 1];
    int g = lane >> 4, sub = lane & 15;
    const uint4* hp = (const uint4*)src;          // 16 B = 8 halves per element
    float a0=0.f,a1=0.f,a2=0.f,a3=0.f,a4=0.f,a5=0.f,a6=0.f,a7=0.f;

    auto accum = [&](uint4 u) {
        __half2 p0 = *(__half2*)&u.x, p1 = *(__half2*)&u.y;
        __half2 p2 = *(__half2*)&u.z, p3 = *(__half2*)&u.w;
        float2 f0 = __half22float2(p0), f1 = __half22float2(p1);
        float2 f2 = __half22float2(p2), f3 = __half22float2(p3);
        a0 += f0.x; a1 += f0.y; a2 += f1.x; a3 += f1.y;
        a4 += f2.x; a5 += f2.y; a6 += f3.x; a7 += f3.y;
    };

    if (g == 0) accum(hp[(size_t)c * 16 + sub]);   // self loop (dc folded)

    int i = beg;
    for (; i + 16 <= end; i += 16) {               // 4 edges per group
        int base = i + 4 * g;
        int r0 = sorted_r[base + 0];
        int r1 = sorted_r[base + 1];
        int r2 = sorted_r[base + 2];
        int r3 = sorted_r[base + 3];
        uint4 u0 = hp[(size_t)r0 * 16 + sub];
        uint4 u1 = hp[(size_t)r1 * 16 + sub];
        uint4 u2 = hp[(size_t)r2 * 16 + sub];
        uint4 u3 = hp[(size_t)r3 * 16 + sub];
        accum(u0); accum(u1); accum(u2); accum(u3);
    }
    for (int idx = i + g; idx < end; idx += 4) {   // remainder
        accum(hp[(size_t)sorted_r[idx] * 16 + sub]);
    }
    a0 += __shfl_xor(a0, 32); a1 += __shfl_xor(a1, 32);
    a2 += __shfl_xor(a2, 32); a3 += __shfl_xor(a3, 32);
    a4 += __shfl_xor(a4, 32); a5 += __shfl_xor(a5, 32);
    a6 += __shfl_xor(a6, 32); a7 += __shfl_xor(a7, 32);
    a0 += __shfl_xor(a0, 16); a1 += __shfl_xor(a1, 16);
    a2 += __shfl_xor(a2, 16); a3 += __shfl_xor(a3, 16);
    a4 += __shfl_xor(a4, 16); a5 += __shfl_xor(a5, 16);
    a6 += __shfl_xor(a6, 16); a7 += __shfl_xor(a7, 16);
    if (g == 0) {
        float dc = dinv[c];
        __half2 h01 = __floats2half2_rn(a0 * dc, a1 * dc);
        __half2 h23 = __floats2half2_rn(a2 * dc, a3 * dc);
        __half2 h45 = __floats2half2_rn(a4 * dc, a5 * dc);
        __half2 h67 = __floats2half2_rn(a6 * dc, a7 * dc);
        uint4 o;
        o.x = *(unsigned int*)&h01; o.y = *(unsigned int*)&h23;
        o.z = *(unsigned int*)&h45; o.w = *(unsigned int*)&h67;
        ((uint4*)dst)[(size_t)c * 16 + sub] = o;
    }
}

// --------------------------------------------- pooling stage 1: partial sums
__global__ __launch_bounds__(256) void pool_partial(const __half* __restrict__ h,
                                                    const int* __restrict__ batch,
                                                    float* __restrict__ partials, int N) {
    int g = blockIdx.x >> 3, part8 = blockIdx.x & 7;
    int t = threadIdx.x, cp = t & 63, rp = t >> 6;   // 4 row-parts, 64 ch-pairs
    int lo = 0, hi = N;
    while (lo < hi) { int m = (lo + hi) >> 1; if (batch[m] < g) lo = m + 1; else hi = m; }
    int beg = lo;
    lo = beg; hi = N;
    while (lo < hi) { int m = (lo + hi) >> 1; if (batch[m] < g + 1) lo = m + 1; else hi = m; }
    int end = lo;
    const __half2* h2 = (const __half2*)h;
    float ax = 0.f, ay = 0.f;
    for (int i = beg + part8 * 4 + rp; i < end; i += 32) {
        float2 v = __half22float2(h2[(size_t)i * 64 + cp]);
        ax += v.x; ay += v.y;
    }
    __shared__ float px[4][64], py[4][64];
    px[rp][cp] = ax; py[rp][cp] = ay;
    __syncthreads();
    if (rp == 0) {
        float sx = px[0][cp] + px[1][cp] + px[2][cp] + px[3][cp];
        float sy = py[0][cp] + py[1][cp] + py[2][cp] + py[3][cp];
        partials[(size_t)blockIdx.x * 128 + cp * 2]     = sx;
        partials[(size_t)blockIdx.x * 128 + cp * 2 + 1] = sy;
    }
}

// ------------------------------------------------- pooling stage 2 + MLP head
__global__ __launch_bounds__(128) void head_kernel(const float* __restrict__ partials,
                                                   const int* __restrict__ batch,
                                                   const float* __restrict__ b4,
                                                   const float* __restrict__ Wd1,
                                                   const float* __restrict__ bd1,
                                                   const float* __restrict__ Wd2,
                                                   const float* __restrict__ bd2,
                                                   const float* __restrict__ Wo,
                                                   const float* __restrict__ bo,
                                                   float* __restrict__ out, int N) {
    int g = blockIdx.x;
    int j = threadIdx.x;
    __shared__ float sA[128], sB[128], red[128];
    int lo = 0, hi = N;
    while (lo < hi) { int m = (lo + hi) >> 1; if (batch[m] < g) lo = m + 1; else hi = m; }
    int beg = lo;
    lo = beg; hi = N;
    while (lo < hi) { int m = (lo + hi) >> 1; if (batch[m] < g + 1) lo = m + 1; else hi = m; }
    int cnt = lo - beg;
    float s = 0.f;
#pragma unroll
    for (int p = 0; p < 8; ++p) s += partials[(size_t)(g * 8 + p) * 128 + j];
    sA[j] = (cnt > 0) ? s / (float)cnt + b4[j] : 0.f;
    __syncthreads();
    float a = bd1[j];
#pragma unroll 4
    for (int k = 0; k < 128; ++k) a += sA[k] * Wd1[k * HIDDEN + j];
    sB[j] = fmaxf(a, 0.f);
    __syncthreads();
    a = bd2[j];
#pragma unroll 4
    for (int k = 0; k < 128; ++k) a += sB[k] * Wd2[k * HIDDEN + j];
    red[j] = fmaxf(a, 0.f) * Wo[j];
    __syncthreads();
    for (int d = 64; d > 0; d >>= 1) {
        if (j < d) red[j] += red[j + d];
        __syncthreads();
    }
    if (j == 0) out[g] = red[0] + bo[0];
}

// ============================================================================
extern "C" void kernel_launch(void* const* d_in, const int* in_sizes, int n_in,
                              void* d_out, int out_size, void* d_ws, size_t ws_size,
                              hipStream_t stream) {
    const float* x   = (const float*)d_in[0];
    const int*   ei  = (const int*)d_in[1];
    const int*   bat = (const int*)d_in[2];
    const float* W1  = (const float*)d_in[3];
    const float* b1  = (const float*)d_in[4];
    const float* W2  = (const float*)d_in[5];
    const float* b2  = (const float*)d_in[6];
    const float* W4  = (const float*)d_in[7];
    const float* b4  = (const float*)d_in[8];
    const float* Wd1 = (const float*)d_in[9];
    const float* bd1 = (const float*)d_in[10];
    const float* Wd2 = (const float*)d_in[11];
    const float* bd2 = (const float*)d_in[12];
    const float* Wo  = (const float*)d_in[13];
    const float* bo  = (const float*)d_in[14];
    float* out = (float*)d_out;

    const int N = in_sizes[0] / 11;
    const int E = in_sizes[1] / 2;
    const int* row = ei;
    const int* col = ei + E;

    size_t off = 0;
    auto carve = [&](size_t bytes) {
        void* p = (char*)d_ws + off;
        off += (bytes + 255) & ~(size_t)255;
        return p;
    };
    __half* bufHA    = (__half*)carve((size_t)N * HIDDEN * 2);
    __half* bufHB    = (__half*)carve((size_t)N * HIDDEN * 2);
    __half* xp       = (__half*)carve((size_t)N * 16 * 2);
    float*  aggx     = (float*)carve((size_t)N * 16 * 4);
    int*    deg      = (int*)carve((size_t)N * 4);
    int*    offsets  = (int*)carve((size_t)(N + 1) * 4);
    int*    cursor   = (int*)carve((size_t)N * 4);
    float*  dinv     = (float*)carve((size_t)N * 4);
    int*    sorted_r = (int*)carve((size_t)E * 4);
    int*    bsums    = (int*)carve((size_t)1024 * 4);
    float*  partials = (float*)carve((size_t)128 * 8 * 128 * 4);
    (void)ws_size; (void)n_in; (void)out_size;

    // ---- build CSR (reused by all 3 layers)
    hipMemsetAsync(deg, 0, (size_t)N * 4, stream);
    count_kernel<<<(E + 255) / 256, 256, 0, stream>>>(col, deg, E);
    int scanBlocks = (N + 1023) / 1024;
    scan_blocksums<<<scanBlocks, 256, 0, stream>>>(deg, bsums, N);
    scan_write<<<scanBlocks, 256, 0, stream>>>(deg, bsums, offsets, cursor, dinv, N, E);
    fill_kernel<<<(E + 255) / 256, 256, 0, stream>>>(row, col, cursor, sorted_r, E);

    int aggBlocks  = (N + 3) / 4;
    int gemmBlocks = (N + 15) / 16;

    // ---- layer 1: aggregate dinv-folded fp16 input, then GEMM (linearity)
    pad_x<<<(N * 16 + 255) / 256, 256, 0, stream>>>(x, dinv, xp, N);
    agg16<<<aggBlocks, 256, 0, stream>>>(xp, aggx, offsets, sorted_r, dinv, N);
    gemm_in_agg<<<(N + 1) / 2, 256, 0, stream>>>(aggx, W1, bufHA, N);
    // ---- layer 2
    gemm128h<<<gemmBlocks, 256, 0, stream>>>(bufHA, b1, W2, dinv, bufHB, N);
    agg128h<<<aggBlocks, 256, 0, stream>>>(bufHB, bufHA, offsets, sorted_r, dinv, N);
    // ---- layer 3
    gemm128h<<<gemmBlocks, 256, 0, stream>>>(bufHA, b2, W4, dinv, bufHB, N);
    agg128h<<<aggBlocks, 256, 0, stream>>>(bufHB, bufHA, offsets, sorted_r, dinv, N);
    // ---- pool + head
    pool_partial<<<128 * 8, 256, 0, stream>>>(bufHA, bat, partials, N);
    head_kernel<<<128, 128, 0, stream>>>(partials, bat, b4, Wd1, bd1, Wd2, bd2,
                                         Wo, bo, out, N);
}

// Round 7
// 500.746 us; speedup vs baseline: 1.1675x; 1.1675x over previous
//
#include <hip/hip_runtime.h>
#include <hip/hip_fp16.h>

#define HIDDEN 128
#define BSHIFT 8          // bucket = 256 destination nodes
#define CHUNK 6144        // edges per fill_pass1 block

// ---------------------------------------------------------------- degree count
__global__ __launch_bounds__(256) void count_kernel(const int* __restrict__ col,
                                                    int* __restrict__ deg, int E) {
    int e = blockIdx.x * 256 + threadIdx.x;
    if (e < E) atomicAdd(&deg[col[e]], 1);
}

// ----------------------------------------------------- scan phase 1: block sums
__global__ __launch_bounds__(256) void scan_blocksums(const int* __restrict__ deg,
                                                      int* __restrict__ bsums, int N) {
    __shared__ int red[256];
    int t = threadIdx.x;
    int base = blockIdx.x * 1024 + t * 4;
    int s = 0;
    if (base + 3 < N) {
        int4 v = *(const int4*)(deg + base);
        s = v.x + v.y + v.z + v.w;
    } else {
        for (int k = 0; k < 4; ++k) if (base + k < N) s += deg[base + k];
    }
    red[t] = s;
    __syncthreads();
    for (int d = 128; d > 0; d >>= 1) {
        if (t < d) red[t] += red[t + d];
        __syncthreads();
    }
    if (t == 0) bsums[blockIdx.x] = red[0];
}

// ------------------------------------- scan phase 2: write offsets/cursor/dinv
__global__ __launch_bounds__(256) void scan_write(const int* __restrict__ deg,
                                                  const int* __restrict__ bsums,
                                                  int* __restrict__ offsets,
                                                  int* __restrict__ cursor,
                                                  float* __restrict__ dinv,
                                                  int N, int E) {
    __shared__ int incl[256];
    __shared__ int red[256];
    __shared__ int s_boff;
    int t = threadIdx.x;
    int base = blockIdx.x * 1024 + t * 4;
    int d0 = 0, d1 = 0, d2 = 0, d3 = 0;
    if (base + 3 < N) {
        int4 v = *(const int4*)(deg + base);
        d0 = v.x; d1 = v.y; d2 = v.z; d3 = v.w;
    } else {
        if (base + 0 < N) d0 = deg[base + 0];
        if (base + 1 < N) d1 = deg[base + 1];
        if (base + 2 < N) d2 = deg[base + 2];
        if (base + 3 < N) d3 = deg[base + 3];
    }
    int mysum = d0 + d1 + d2 + d3;
    incl[t] = mysum;
    int b = 0;
    for (int i = t; i < blockIdx.x; i += 256) b += bsums[i];
    red[t] = b;
    __syncthreads();
    for (int d = 128; d > 0; d >>= 1) {
        if (t < d) red[t] += red[t + d];
        __syncthreads();
    }
    if (t == 0) s_boff = red[0];
    for (int d = 1; d < 256; d <<= 1) {
        int v = (t >= d) ? incl[t - d] : 0;
        __syncthreads();
        incl[t] += v;
        __syncthreads();
    }
    int run = s_boff + incl[t] - mysum;
    if (base + 0 < N) { offsets[base + 0] = run; cursor[base + 0] = run; dinv[base + 0] = rsqrtf((float)(d0 + 1)); run += d0; }
    if (base + 1 < N) { offsets[base + 1] = run; cursor[base + 1] = run; dinv[base + 1] = rsqrtf((float)(d1 + 1)); run += d1; }
    if (base + 2 < N) { offsets[base + 2] = run; cursor[base + 2] = run; dinv[base + 2] = rsqrtf((float)(d2 + 1)); run += d2; }
    if (base + 3 < N) { offsets[base + 3] = run; cursor[base + 3] = run; dinv[base + 3] = rsqrtf((float)(d3 + 1)); run += d3; }
    if (blockIdx.x == 0 && t == 0) offsets[N] = E;
}

// ------------------------------------- bucket cursors: gcur[b] = offsets[b*256]
__global__ __launch_bounds__(256) void init_gcur(const int* __restrict__ offsets,
                                                 int* __restrict__ gcur, int N) {
    int b = blockIdx.x * 256 + threadIdx.x;
    if (b < 512) {
        int node = min(b << BSHIFT, N);
        gcur[b] = offsets[node];
    }
}

// -------------------- fill pass 1: LDS-bin edges into 256-node bucket regions
// pairs[] has the final CSR layout at bucket granularity (unordered inside).
__global__ __launch_bounds__(256) void fill_pass1(const int* __restrict__ row,
                                                  const int* __restrict__ col,
                                                  int* __restrict__ gcur,
                                                  int2* __restrict__ pairs, int E) {
    __shared__ int cnt[512], start[512], place[512], gbase[512];
    __shared__ int ssum[256];
    __shared__ int2 stage[CHUNK];
    int t = threadIdx.x;
    int e0 = blockIdx.x * CHUNK;
    int e1 = min(e0 + CHUNK, E);
    cnt[t] = 0; cnt[t + 256] = 0;
    __syncthreads();
    // count buckets
    for (int e = e0 + t; e < e1; e += 256)
        atomicAdd(&cnt[col[e] >> BSHIFT], 1);
    __syncthreads();
    // exclusive scan of 512 counters (pairwise + Hillis-Steele on 256)
    int s2 = cnt[2 * t] + cnt[2 * t + 1];
    ssum[t] = s2;
    __syncthreads();
    for (int d = 1; d < 256; d <<= 1) {
        int v = (t >= d) ? ssum[t - d] : 0;
        __syncthreads();
        ssum[t] += v;
        __syncthreads();
    }
    int excl = ssum[t] - s2;
    start[2 * t] = excl;
    start[2 * t + 1] = excl + cnt[2 * t];
    place[2 * t] = excl;
    place[2 * t + 1] = excl + cnt[2 * t];
    __syncthreads();
    // stage pairs bucket-contiguously in LDS
    for (int e = e0 + t; e < e1; e += 256) {
        int c = col[e], r = row[e];
        int slot = atomicAdd(&place[c >> BSHIFT], 1);
        stage[slot] = make_int2(r, c);
    }
    // reserve global space per bucket (cnt stable since count-phase sync)
    {
        int c0 = cnt[t], c1 = cnt[t + 256];
        if (c0 > 0) gbase[t] = atomicAdd(&gcur[t], c0);
        if (c1 > 0) gbase[t + 256] = atomicAdd(&gcur[t + 256], c1);
    }
    __syncthreads();
    // stream out: bucket runs are contiguous in both LDS and global
    int n = e1 - e0;
    for (int i = t; i < n; i += 256) {
        int2 p = stage[i];
        int b = p.y >> BSHIFT;
        pairs[gbase[b] + (i - start[b])] = p;
    }
}

// ------------- fill pass 2: one block per bucket; XCD-local fine scatter
__global__ __launch_bounds__(256) void fill_pass2(const int2* __restrict__ pairs,
                                                  const int* __restrict__ offsets,
                                                  int* __restrict__ cursor,
                                                  int* __restrict__ sorted_r, int N) {
    int b = blockIdx.x;
    int nlo = min(b << BSHIFT, N), nhi = min(nlo + (1 << BSHIFT), N);
    int p0 = offsets[nlo], p1 = offsets[nhi];
    for (int i = p0 + threadIdx.x; i < p1; i += 256) {
        int2 pr = pairs[i];
        int p = atomicAdd(&cursor[pr.y], 1);
        sorted_r[p] = pr.x;
    }
}

// ----------------- pad x [N,11] -> fp16 [N,16], folding dinv[i] into the row
__global__ __launch_bounds__(256) void pad_x(const float* __restrict__ x,
                                             const float* __restrict__ dinv,
                                             __half* __restrict__ xp, int N) {
    int q = blockIdx.x * 256 + threadIdx.x;
    if (q >= N * 16) return;
    int i = q >> 4, c = q & 15;
    float v = (c < 11) ? x[(size_t)i * 11 + c] * dinv[i] : 0.f;
    xp[q] = __float2half(v);
}

// -------------------- aggregate 16-ch dinv-folded input: aggx[c]=dc*(sum+self)
__global__ __launch_bounds__(256) void agg16(const __half* __restrict__ xp,
                                             float* __restrict__ aggx,
                                             const int* __restrict__ offsets,
                                             const int* __restrict__ sorted_r,
                                             const float* __restrict__ dinv, int N) {
    int wid  = (blockIdx.x * 256 + threadIdx.x) >> 6;
    int lane = threadIdx.x & 63;
    if (wid >= N) return;
    int c = wid;
    int g = lane >> 3, cp = lane & 7;
    int beg = offsets[c], end = offsets[c + 1];
    const __half2* xp2 = (const __half2*)xp;
    float ax = 0.f, ay = 0.f;
    if (g == 0) {
        float2 v = __half22float2(xp2[(size_t)c * 8 + cp]);   // self (dc folded)
        ax = v.x; ay = v.y;
    }
    for (int idx = beg + g; idx < end; idx += 8) {
        int r = sorted_r[idx];
        float2 v = __half22float2(xp2[(size_t)r * 8 + cp]);
        ax += v.x; ay += v.y;
    }
    ax += __shfl_xor(ax, 32); ay += __shfl_xor(ay, 32);
    ax += __shfl_xor(ax, 16); ay += __shfl_xor(ay, 16);
    ax += __shfl_xor(ax, 8);  ay += __shfl_xor(ay, 8);
    if (lane < 8) {
        float dc = dinv[c];
        aggx[(size_t)c * 16 + cp * 2]     = ax * dc;
        aggx[(size_t)c * 16 + cp * 2 + 1] = ay * dc;
    }
}

// ---------------------------- GEMM: h1 = aggx[:, :11] @ W1 -> fp16 (conv1 out)
__global__ __launch_bounds__(256) void gemm_in_agg(const float* __restrict__ aggx,
                                                   const float* __restrict__ W1,
                                                   __half* __restrict__ out, int N) {
    int i = blockIdx.x * 2 + (threadIdx.x >> 7);
    int j = threadIdx.x & 127;
    if (i >= N) return;
    float acc = 0.f;
#pragma unroll
    for (int c = 0; c < 11; ++c) acc += aggx[(size_t)i * 16 + c] * W1[c * HIDDEN + j];
    out[(size_t)i * HIDDEN + j] = __float2half(acc);
}

// ------- GEMM: out_fp16 = dinv[i] * ( relu(H_fp16 + b) @ W )  (fp32 accumulate)
__global__ __launch_bounds__(256) void gemm128h(const __half* __restrict__ H,
                                                const float* __restrict__ bias,
                                                const float* __restrict__ W,
                                                const float* __restrict__ dinv,
                                                __half* __restrict__ out, int N) {
    __shared__ float Hlds[16][HIDDEN];   // 8 KB
    int t = threadIdx.x;
    int rowbase = blockIdx.x * 16;
    const __half2* H2 = (const __half2*)H;
    for (int q = t; q < 16 * 64; q += 256) {
        int r = q >> 6, kp = q & 63;
        int gr = rowbase + r;
        float2 v = make_float2(0.f, 0.f);
        if (gr < N) v = __half22float2(H2[(size_t)gr * 64 + kp]);
        Hlds[r][kp * 2]     = fmaxf(v.x + bias[kp * 2], 0.f);
        Hlds[r][kp * 2 + 1] = fmaxf(v.y + bias[kp * 2 + 1], 0.f);
    }
    __syncthreads();
    int j  = t & 127;
    int rb = t >> 7;
    float acc[8] = {0.f, 0.f, 0.f, 0.f, 0.f, 0.f, 0.f, 0.f};
#pragma unroll 4
    for (int k = 0; k < HIDDEN; ++k) {
        float wv = W[k * HIDDEN + j];
#pragma unroll
        for (int m = 0; m < 8; ++m) acc[m] += Hlds[rb + 2 * m][k] * wv;
    }
#pragma unroll
    for (int m = 0; m < 8; ++m) {
        int gr = rowbase + rb + 2 * m;
        if (gr < N) out[(size_t)gr * HIDDEN + j] = __float2half(acc[m] * dinv[gr]);
    }
}

// -------- aggregation 128ch fp16, no edge weights (dinv folded into features)
__global__ __launch_bounds__(256) void agg128h(const __half* __restrict__ src,
                                               __half* __restrict__ dst,
                                               const int* __restrict__ offsets,
                                               const int* __restrict__ sorted_r,
                                               const float* __restrict__ dinv, int N) {
    int wid  = (blockIdx.x * 256 + threadIdx.x) >> 6;
    int lane = threadIdx.x & 63;
    if (wid >= N) return;
    int c = wid;
    int beg = offsets[c], end = offsets[c + 1];
    int g = lane >> 4, sub = lane & 15;
    const uint4* hp = (const uint4*)src;          // 16 B = 8 halves per element
    float a0=0.f,a1=0.f,a2=0.f,a3=0.f,a4=0.f,a5=0.f,a6=0.f,a7=0.f;

    auto accum = [&](uint4 u) {
        __half2 p0 = *(__half2*)&u.x, p1 = *(__half2*)&u.y;
        __half2 p2 = *(__half2*)&u.z, p3 = *(__half2*)&u.w;
        float2 f0 = __half22float2(p0), f1 = __half22float2(p1);
        float2 f2 = __half22float2(p2), f3 = __half22float2(p3);
        a0 += f0.x; a1 += f0.y; a2 += f1.x; a3 += f1.y;
        a4 += f2.x; a5 += f2.y; a6 += f3.x; a7 += f3.y;
    };

    if (g == 0) accum(hp[(size_t)c * 16 + sub]);   // self loop (dc folded)

    int i = beg;
    for (; i + 16 <= end; i += 16) {               // 4 edges per group
        int base = i + 4 * g;
        int r0 = sorted_r[base + 0];
        int r1 = sorted_r[base + 1];
        int r2 = sorted_r[base + 2];
        int r3 = sorted_r[base + 3];
        uint4 u0 = hp[(size_t)r0 * 16 + sub];
        uint4 u1 = hp[(size_t)r1 * 16 + sub];
        uint4 u2 = hp[(size_t)r2 * 16 + sub];
        uint4 u3 = hp[(size_t)r3 * 16 + sub];
        accum(u0); accum(u1); accum(u2); accum(u3);
    }
    for (int idx = i + g; idx < end; idx += 4) {   // remainder
        accum(hp[(size_t)sorted_r[idx] * 16 + sub]);
    }
    a0 += __shfl_xor(a0, 32); a1 += __shfl_xor(a1, 32);
    a2 += __shfl_xor(a2, 32); a3 += __shfl_xor(a3, 32);
    a4 += __shfl_xor(a4, 32); a5 += __shfl_xor(a5, 32);
    a6 += __shfl_xor(a6, 32); a7 += __shfl_xor(a7, 32);
    a0 += __shfl_xor(a0, 16); a1 += __shfl_xor(a1, 16);
    a2 += __shfl_xor(a2, 16); a3 += __shfl_xor(a3, 16);
    a4 += __shfl_xor(a4, 16); a5 += __shfl_xor(a5, 16);
    a6 += __shfl_xor(a6, 16); a7 += __shfl_xor(a7, 16);
    if (g == 0) {
        float dc = dinv[c];
        __half2 h01 = __floats2half2_rn(a0 * dc, a1 * dc);
        __half2 h23 = __floats2half2_rn(a2 * dc, a3 * dc);
        __half2 h45 = __floats2half2_rn(a4 * dc, a5 * dc);
        __half2 h67 = __floats2half2_rn(a6 * dc, a7 * dc);
        uint4 o;
        o.x = *(unsigned int*)&h01; o.y = *(unsigned int*)&h23;
        o.z = *(unsigned int*)&h45; o.w = *(unsigned int*)&h67;
        ((uint4*)dst)[(size_t)c * 16 + sub] = o;
    }
}

// --------------------------------------------- pooling stage 1: partial sums
__global__ __launch_bounds__(256) void pool_partial(const __half* __restrict__ h,
                                                    const int* __restrict__ batch,
                                                    float* __restrict__ partials, int N) {
    int g = blockIdx.x >> 3, part8 = blockIdx.x & 7;
    int t = threadIdx.x, cp = t & 63, rp = t >> 6;   // 4 row-parts, 64 ch-pairs
    int lo = 0, hi = N;
    while (lo < hi) { int m = (lo + hi) >> 1; if (batch[m] < g) lo = m + 1; else hi = m; }
    int beg = lo;
    lo = beg; hi = N;
    while (lo < hi) { int m = (lo + hi) >> 1; if (batch[m] < g + 1) lo = m + 1; else hi = m; }
    int end = lo;
    const __half2* h2 = (const __half2*)h;
    float ax = 0.f, ay = 0.f;
    for (int i = beg + part8 * 4 + rp; i < end; i += 32) {
        float2 v = __half22float2(h2[(size_t)i * 64 + cp]);
        ax += v.x; ay += v.y;
    }
    __shared__ float px[4][64], py[4][64];
    px[rp][cp] = ax; py[rp][cp] = ay;
    __syncthreads();
    if (rp == 0) {
        float sx = px[0][cp] + px[1][cp] + px[2][cp] + px[3][cp];
        float sy = py[0][cp] + py[1][cp] + py[2][cp] + py[3][cp];
        partials[(size_t)blockIdx.x * 128 + cp * 2]     = sx;
        partials[(size_t)blockIdx.x * 128 + cp * 2 + 1] = sy;
    }
}

// ------------------------------------------------- pooling stage 2 + MLP head
__global__ __launch_bounds__(128) void head_kernel(const float* __restrict__ partials,
                                                   const int* __restrict__ batch,
                                                   const float* __restrict__ b4,
                                                   const float* __restrict__ Wd1,
                                                   const float* __restrict__ bd1,
                                                   const float* __restrict__ Wd2,
                                                   const float* __restrict__ bd2,
                                                   const float* __restrict__ Wo,
                                                   const float* __restrict__ bo,
                                                   float* __restrict__ out, int N) {
    int g = blockIdx.x;
    int j = threadIdx.x;
    __shared__ float sA[128], sB[128], red[128];
    int lo = 0, hi = N;
    while (lo < hi) { int m = (lo + hi) >> 1; if (batch[m] < g) lo = m + 1; else hi = m; }
    int beg = lo;
    lo = beg; hi = N;
    while (lo < hi) { int m = (lo + hi) >> 1; if (batch[m] < g + 1) lo = m + 1; else hi = m; }
    int cnt = lo - beg;
    float s = 0.f;
#pragma unroll
    for (int p = 0; p < 8; ++p) s += partials[(size_t)(g * 8 + p) * 128 + j];
    sA[j] = (cnt > 0) ? s / (float)cnt + b4[j] : 0.f;
    __syncthreads();
    float a = bd1[j];
#pragma unroll 4
    for (int k = 0; k < 128; ++k) a += sA[k] * Wd1[k * HIDDEN + j];
    sB[j] = fmaxf(a, 0.f);
    __syncthreads();
    a = bd2[j];
#pragma unroll 4
    for (int k = 0; k < 128; ++k) a += sB[k] * Wd2[k * HIDDEN + j];
    red[j] = fmaxf(a, 0.f) * Wo[j];
    __syncthreads();
    for (int d = 64; d > 0; d >>= 1) {
        if (j < d) red[j] += red[j + d];
        __syncthreads();
    }
    if (j == 0) out[g] = red[0] + bo[0];
}

// ============================================================================
extern "C" void kernel_launch(void* const* d_in, const int* in_sizes, int n_in,
                              void* d_out, int out_size, void* d_ws, size_t ws_size,
                              hipStream_t stream) {
    const float* x   = (const float*)d_in[0];
    const int*   ei  = (const int*)d_in[1];
    const int*   bat = (const int*)d_in[2];
    const float* W1  = (const float*)d_in[3];
    const float* b1  = (const float*)d_in[4];
    const float* W2  = (const float*)d_in[5];
    const float* b2  = (const float*)d_in[6];
    const float* W4  = (const float*)d_in[7];
    const float* b4  = (const float*)d_in[8];
    const float* Wd1 = (const float*)d_in[9];
    const float* bd1 = (const float*)d_in[10];
    const float* Wd2 = (const float*)d_in[11];
    const float* bd2 = (const float*)d_in[12];
    const float* Wo  = (const float*)d_in[13];
    const float* bo  = (const float*)d_in[14];
    float* out = (float*)d_out;

    const int N = in_sizes[0] / 11;
    const int E = in_sizes[1] / 2;
    const int* row = ei;
    const int* col = ei + E;
    const int B = (N + (1 << BSHIFT) - 1) >> BSHIFT;   // #buckets

    size_t off = 0;
    auto carve = [&](size_t bytes) {
        void* p = (char*)d_ws + off;
        off += (bytes + 255) & ~(size_t)255;
        return p;
    };
    __half* bufHA    = (__half*)carve((size_t)N * HIDDEN * 2);
    __half* bufHB    = (__half*)carve((size_t)N * HIDDEN * 2);
    __half* xp       = (__half*)carve((size_t)N * 16 * 2);
    float*  aggx     = (float*)carve((size_t)N * 16 * 4);
    int*    deg      = (int*)carve((size_t)N * 4);
    int*    offsets  = (int*)carve((size_t)(N + 1) * 4);
    int*    cursor   = (int*)carve((size_t)N * 4);
    float*  dinv     = (float*)carve((size_t)N * 4);
    int*    sorted_r = (int*)carve((size_t)E * 4);
    int2*   pairs    = (int2*)carve((size_t)E * 8);
    int*    gcur     = (int*)carve((size_t)512 * 4);
    int*    bsums    = (int*)carve((size_t)1024 * 4);
    float*  partials = (float*)carve((size_t)128 * 8 * 128 * 4);
    (void)ws_size; (void)n_in; (void)out_size;

    // ---- build CSR (reused by all 3 layers)
    hipMemsetAsync(deg, 0, (size_t)N * 4, stream);
    count_kernel<<<(E + 255) / 256, 256, 0, stream>>>(col, deg, E);
    int scanBlocks = (N + 1023) / 1024;
    scan_blocksums<<<scanBlocks, 256, 0, stream>>>(deg, bsums, N);
    scan_write<<<scanBlocks, 256, 0, stream>>>(deg, bsums, offsets, cursor, dinv, N, E);
    init_gcur<<<2, 256, 0, stream>>>(offsets, gcur, N);
    fill_pass1<<<(E + CHUNK - 1) / CHUNK, 256, 0, stream>>>(row, col, gcur, pairs, E);
    fill_pass2<<<B, 256, 0, stream>>>(pairs, offsets, cursor, sorted_r, N);

    int aggBlocks  = (N + 3) / 4;
    int gemmBlocks = (N + 15) / 16;

    // ---- layer 1: aggregate dinv-folded fp16 input, then GEMM (linearity)
    pad_x<<<(N * 16 + 255) / 256, 256, 0, stream>>>(x, dinv, xp, N);
    agg16<<<aggBlocks, 256, 0, stream>>>(xp, aggx, offsets, sorted_r, dinv, N);
    gemm_in_agg<<<(N + 1) / 2, 256, 0, stream>>>(aggx, W1, bufHA, N);
    // ---- layer 2
    gemm128h<<<gemmBlocks, 256, 0, stream>>>(bufHA, b1, W2, dinv, bufHB, N);
    agg128h<<<aggBlocks, 256, 0, stream>>>(bufHB, bufHA, offsets, sorted_r, dinv, N);
    // ---- layer 3
    gemm128h<<<gemmBlocks, 256, 0, stream>>>(bufHA, b2, W4, dinv, bufHB, N);
    agg128h<<<aggBlocks, 256, 0, stream>>>(bufHB, bufHA, offsets, sorted_r, dinv, N);
    // ---- pool + head
    pool_partial<<<128 * 8, 256, 0, stream>>>(bufHA, bat, partials, N);
    head_kernel<<<128, 128, 0, stream>>>(partials, bat, b4, Wd1, bd1, Wd2, bd2,
                                         Wo, bo, out, N);
}

// Round 9
// 424.669 us; speedup vs baseline: 1.3766x; 1.1791x over previous
//
#include <hip/hip_runtime.h>
#include <hip/hip_fp16.h>

#define HIDDEN 128
#define BSHIFT 8          // bucket = 256 destination nodes
#define CHUNK 6144        // edges per fill_pass1 block

typedef _Float16 h8 __attribute__((ext_vector_type(8)));
typedef float f4x __attribute__((ext_vector_type(4)));

// ---------------------------------------------------------------- degree count
__global__ __launch_bounds__(256) void count_kernel(const int* __restrict__ col,
                                                    int* __restrict__ deg, int E) {
    int e = blockIdx.x * 256 + threadIdx.x;
    if (e < E) atomicAdd(&deg[col[e]], 1);
}

// ----------------------------------------------------- scan phase 1: block sums
__global__ __launch_bounds__(256) void scan_blocksums(const int* __restrict__ deg,
                                                      int* __restrict__ bsums, int N) {
    __shared__ int red[256];
    int t = threadIdx.x;
    int base = blockIdx.x * 1024 + t * 4;
    int s = 0;
    if (base + 3 < N) {
        int4 v = *(const int4*)(deg + base);
        s = v.x + v.y + v.z + v.w;
    } else {
        for (int k = 0; k < 4; ++k) if (base + k < N) s += deg[base + k];
    }
    red[t] = s;
    __syncthreads();
    for (int d = 128; d > 0; d >>= 1) {
        if (t < d) red[t] += red[t + d];
        __syncthreads();
    }
    if (t == 0) bsums[blockIdx.x] = red[0];
}

// ------------------------------------- scan phase 2: write offsets/cursor/dinv
__global__ __launch_bounds__(256) void scan_write(const int* __restrict__ deg,
                                                  const int* __restrict__ bsums,
                                                  int* __restrict__ offsets,
                                                  int* __restrict__ cursor,
                                                  float* __restrict__ dinv,
                                                  int N, int E) {
    __shared__ int incl[256];
    __shared__ int red[256];
    __shared__ int s_boff;
    int t = threadIdx.x;
    int base = blockIdx.x * 1024 + t * 4;
    int d0 = 0, d1 = 0, d2 = 0, d3 = 0;
    if (base + 3 < N) {
        int4 v = *(const int4*)(deg + base);
        d0 = v.x; d1 = v.y; d2 = v.z; d3 = v.w;
    } else {
        if (base + 0 < N) d0 = deg[base + 0];
        if (base + 1 < N) d1 = deg[base + 1];
        if (base + 2 < N) d2 = deg[base + 2];
        if (base + 3 < N) d3 = deg[base + 3];
    }
    int mysum = d0 + d1 + d2 + d3;
    incl[t] = mysum;
    int b = 0;
    for (int i = t; i < blockIdx.x; i += 256) b += bsums[i];
    red[t] = b;
    __syncthreads();
    for (int d = 128; d > 0; d >>= 1) {
        if (t < d) red[t] += red[t + d];
        __syncthreads();
    }
    if (t == 0) s_boff = red[0];
    for (int d = 1; d < 256; d <<= 1) {
        int v = (t >= d) ? incl[t - d] : 0;
        __syncthreads();
        incl[t] += v;
        __syncthreads();
    }
    int run = s_boff + incl[t] - mysum;
    if (base + 0 < N) { offsets[base + 0] = run; cursor[base + 0] = run; dinv[base + 0] = rsqrtf((float)(d0 + 1)); run += d0; }
    if (base + 1 < N) { offsets[base + 1] = run; cursor[base + 1] = run; dinv[base + 1] = rsqrtf((float)(d1 + 1)); run += d1; }
    if (base + 2 < N) { offsets[base + 2] = run; cursor[base + 2] = run; dinv[base + 2] = rsqrtf((float)(d2 + 1)); run += d2; }
    if (base + 3 < N) { offsets[base + 3] = run; cursor[base + 3] = run; dinv[base + 3] = rsqrtf((float)(d3 + 1)); run += d3; }
    if (blockIdx.x == 0 && t == 0) offsets[N] = E;
}

// ------------------------------------- bucket cursors: gcur[b] = offsets[b*256]
__global__ __launch_bounds__(256) void init_gcur(const int* __restrict__ offsets,
                                                 int* __restrict__ gcur, int N) {
    int b = blockIdx.x * 256 + threadIdx.x;
    if (b < 512) {
        int node = min(b << BSHIFT, N);
        gcur[b] = offsets[node];
    }
}

// -------------------- fill pass 1: LDS-bin edges into 256-node bucket regions
__global__ __launch_bounds__(256) void fill_pass1(const int* __restrict__ row,
                                                  const int* __restrict__ col,
                                                  int* __restrict__ gcur,
                                                  int2* __restrict__ pairs, int E) {
    __shared__ int cnt[512], start[512], place[512], gbase[512];
    __shared__ int ssum[256];
    __shared__ int2 stage[CHUNK];
    int t = threadIdx.x;
    int e0 = blockIdx.x * CHUNK;
    int e1 = min(e0 + CHUNK, E);
    cnt[t] = 0; cnt[t + 256] = 0;
    __syncthreads();
    for (int e = e0 + t; e < e1; e += 256)
        atomicAdd(&cnt[col[e] >> BSHIFT], 1);
    __syncthreads();
    int s2 = cnt[2 * t] + cnt[2 * t + 1];
    ssum[t] = s2;
    __syncthreads();
    for (int d = 1; d < 256; d <<= 1) {
        int v = (t >= d) ? ssum[t - d] : 0;
        __syncthreads();
        ssum[t] += v;
        __syncthreads();
    }
    int excl = ssum[t] - s2;
    start[2 * t] = excl;
    start[2 * t + 1] = excl + cnt[2 * t];
    place[2 * t] = excl;
    place[2 * t + 1] = excl + cnt[2 * t];
    __syncthreads();
    for (int e = e0 + t; e < e1; e += 256) {
        int c = col[e], r = row[e];
        int slot = atomicAdd(&place[c >> BSHIFT], 1);
        stage[slot] = make_int2(r, c);
    }
    {
        int c0 = cnt[t], c1 = cnt[t + 256];
        if (c0 > 0) gbase[t] = atomicAdd(&gcur[t], c0);
        if (c1 > 0) gbase[t + 256] = atomicAdd(&gcur[t + 256], c1);
    }
    __syncthreads();
    int n = e1 - e0;
    for (int i = t; i < n; i += 256) {
        int2 p = stage[i];
        int b = p.y >> BSHIFT;
        pairs[gbase[b] + (i - start[b])] = p;
    }
}

// ------------- fill pass 2: one block per bucket; XCD-local fine scatter
__global__ __launch_bounds__(256) void fill_pass2(const int2* __restrict__ pairs,
                                                  const int* __restrict__ offsets,
                                                  int* __restrict__ cursor,
                                                  int* __restrict__ sorted_r, int N) {
    int b = blockIdx.x;
    int nlo = min(b << BSHIFT, N), nhi = min(nlo + (1 << BSHIFT), N);
    int p0 = offsets[nlo], p1 = offsets[nhi];
    for (int i = p0 + threadIdx.x; i < p1; i += 256) {
        int2 pr = pairs[i];
        int p = atomicAdd(&cursor[pr.y], 1);
        sorted_r[p] = pr.x;
    }
}

// ----------------- pad x [N,11] -> fp16 [N,16], folding dinv[i] into the row
__global__ __launch_bounds__(256) void pad_x(const float* __restrict__ x,
                                             const float* __restrict__ dinv,
                                             __half* __restrict__ xp, int N) {
    int q = blockIdx.x * 256 + threadIdx.x;
    if (q >= N * 16) return;
    int i = q >> 4, c = q & 15;
    float v = (c < 11) ? x[(size_t)i * 11 + c] * dinv[i] : 0.f;
    xp[q] = __float2half(v);
}

// -------------------- aggregate 16-ch dinv-folded input: aggx[c]=dc*(sum+self)
__global__ __launch_bounds__(256) void agg16(const __half* __restrict__ xp,
                                             float* __restrict__ aggx,
                                             const int* __restrict__ offsets,
                                             const int* __restrict__ sorted_r,
                                             const float* __restrict__ dinv, int N) {
    int wid  = (blockIdx.x * 256 + threadIdx.x) >> 6;
    int lane = threadIdx.x & 63;
    if (wid >= N) return;
    int c = wid;
    int g = lane >> 3, cp = lane & 7;
    int beg = offsets[c], end = offsets[c + 1];
    const __half2* xp2 = (const __half2*)xp;
    float ax = 0.f, ay = 0.f;
    if (g == 0) {
        float2 v = __half22float2(xp2[(size_t)c * 8 + cp]);   // self (dc folded)
        ax = v.x; ay = v.y;
    }
    for (int idx = beg + g; idx < end; idx += 8) {
        int r = sorted_r[idx];
        float2 v = __half22float2(xp2[(size_t)r * 8 + cp]);
        ax += v.x; ay += v.y;
    }
    ax += __shfl_xor(ax, 32); ay += __shfl_xor(ay, 32);
    ax += __shfl_xor(ax, 16); ay += __shfl_xor(ay, 16);
    ax += __shfl_xor(ax, 8);  ay += __shfl_xor(ay, 8);
    if (lane < 8) {
        float dc = dinv[c];
        aggx[(size_t)c * 16 + cp * 2]     = ax * dc;
        aggx[(size_t)c * 16 + cp * 2 + 1] = ay * dc;
    }
}

// ---------------------------- GEMM: h1 = aggx[:, :11] @ W1 -> fp16 (conv1 out)
__global__ __launch_bounds__(256) void gemm_in_agg(const float* __restrict__ aggx,
                                                   const float* __restrict__ W1,
                                                   __half* __restrict__ out, int N) {
    int i = blockIdx.x * 2 + (threadIdx.x >> 7);
    int j = threadIdx.x & 127;
    if (i >= N) return;
    float acc = 0.f;
#pragma unroll
    for (int c = 0; c < 11; ++c) acc += aggx[(size_t)i * 16 + c] * W1[c * HIDDEN + j];
    out[(size_t)i * HIDDEN + j] = __float2half(acc);
}

// ---------------- pack W [128][128] fp32 -> MFMA B-fragment order, hi|lo fp16
// entry q = ((s*8+ct)*64 + l), halves i: W[32s+8*(l>>4)+i][16ct+(l&15)]
// layout: [hi 16384 halves][lo 16384 halves][bias_h 128 halves]
__global__ __launch_bounds__(256) void pack_w(const float* __restrict__ W,
                                              const float* __restrict__ bias,
                                              __half* __restrict__ packed) {
    int q = blockIdx.x * 256 + threadIdx.x;
    if (q < 2048) {
        int s = q >> 9, rem = q & 511, ct = rem >> 6, l = rem & 63;
        int b = l >> 4, n = l & 15;
        __half hi8[8], lo8[8];
#pragma unroll
        for (int i = 0; i < 8; ++i) {
            float w = W[(s * 32 + b * 8 + i) * HIDDEN + ct * 16 + n];
            __half h = __float2half(w);
            hi8[i] = h;
            lo8[i] = __float2half(w - __half2float(h));
        }
        *(uint4*)(packed + (size_t)q * 8)         = *(uint4*)hi8;
        *(uint4*)(packed + 16384 + (size_t)q * 8) = *(uint4*)lo8;
    }
    if (q < 128) packed[32768 + q] = __float2half(bias[q]);
}

// ------------- MFMA GEMM: out = fp16( dinv[i] * (relu(H+b) @ (Whi+Wlo)) )
// 4 waves, 128 rows/block, 2 row-tiles/wave, 8 col-tiles, K=128 in 4 steps.
__global__ __launch_bounds__(256) void gemm_mfma(const __half* __restrict__ H,
                                                 const __half* __restrict__ packed,
                                                 const float* __restrict__ dinv,
                                                 __half* __restrict__ out, int N) {
    __shared__ __half Wl[32768];   // hi | lo, 64 KB
    for (int q = threadIdx.x; q < 4096; q += 256)
        ((uint4*)Wl)[q] = ((const uint4*)packed)[q];
    int l = threadIdx.x & 63, wv = threadIdx.x >> 6;
    int m = l & 15, b = l >> 4;
    const __half* bias_h = packed + 32768;
    __syncthreads();

    f4x acc[2][8];
#pragma unroll
    for (int t = 0; t < 2; ++t)
#pragma unroll
        for (int ct = 0; ct < 8; ++ct) acc[t][ct] = (f4x){0.f, 0.f, 0.f, 0.f};

    int rowA0 = blockIdx.x * 128 + wv * 32 + m;

#pragma unroll
    for (int s = 0; s < 4; ++s) {
        uint4 bv = *(const uint4*)(bias_h + s * 32 + b * 8);
        __half2* bh = (__half2*)&bv;
        h8 a[2];
#pragma unroll
        for (int t = 0; t < 2; ++t) {
            int row = rowA0 + t * 16;
            uint4 av = make_uint4(0u, 0u, 0u, 0u);
            if (row < N) av = *(const uint4*)(H + (size_t)row * HIDDEN + s * 32 + b * 8);
            __half2* ah = (__half2*)&av;
#pragma unroll
            for (int p = 0; p < 4; ++p) {
                float2 f  = __half22float2(ah[p]);
                float2 bf = __half22float2(bh[p]);
                ah[p] = __floats2half2_rn(fmaxf(f.x + bf.x, 0.f), fmaxf(f.y + bf.y, 0.f));
            }
            a[t] = *(h8*)&av;
        }
#pragma unroll
        for (int ct = 0; ct < 8; ++ct) {
            h8 whi = *(h8*)&Wl[((s * 8 + ct) * 64 + l) * 8];
            h8 wlo = *(h8*)&Wl[16384 + ((s * 8 + ct) * 64 + l) * 8];
#pragma unroll
            for (int t = 0; t < 2; ++t) {
                acc[t][ct] = __builtin_amdgcn_mfma_f32_16x16x32_f16(a[t], whi, acc[t][ct], 0, 0, 0);
                acc[t][ct] = __builtin_amdgcn_mfma_f32_16x16x32_f16(a[t], wlo, acc[t][ct], 0, 0, 0);
            }
        }
    }
    // epilogue: D row = (lane>>4)*4 + reg, col = ct*16 + (lane&15)
#pragma unroll
    for (int t = 0; t < 2; ++t) {
        int rbase = blockIdx.x * 128 + wv * 32 + t * 16 + b * 4;
#pragma unroll
        for (int i = 0; i < 4; ++i) {
            int row = rbase + i;
            if (row < N) {
                float dv = dinv[row];
#pragma unroll
                for (int ct = 0; ct < 8; ++ct)
                    out[(size_t)row * HIDDEN + ct * 16 + m] = __float2half(acc[t][ct][i] * dv);
            }
        }
    }
}

// -------- aggregation 128ch fp16, no edge weights (dinv folded into features)
__global__ __launch_bounds__(256) void agg128h(const __half* __restrict__ src,
                                               __half* __restrict__ dst,
                                               const int* __restrict__ offsets,
                                               const int* __restrict__ sorted_r,
                                               const float* __restrict__ dinv, int N) {
    int wid  = (blockIdx.x * 256 + threadIdx.x) >> 6;
    int lane = threadIdx.x & 63;
    if (wid >= N) return;
    int c = wid;
    int beg = offsets[c], end = offsets[c + 1];
    int g = lane >> 4, sub = lane & 15;
    const uint4* hp = (const uint4*)src;
    float a0=0.f,a1=0.f,a2=0.f,a3=0.f,a4=0.f,a5=0.f,a6=0.f,a7=0.f;

    auto accum = [&](uint4 u) {
        __half2 p0 = *(__half2*)&u.x, p1 = *(__half2*)&u.y;
        __half2 p2 = *(__half2*)&u.z, p3 = *(__half2*)&u.w;
        float2 f0 = __half22float2(p0), f1 = __half22float2(p1);
        float2 f2 = __half22float2(p2), f3 = __half22float2(p3);
        a0 += f0.x; a1 += f0.y; a2 += f1.x; a3 += f1.y;
        a4 += f2.x; a5 += f2.y; a6 += f3.x; a7 += f3.y;
    };

    if (g == 0) accum(hp[(size_t)c * 16 + sub]);   // self loop (dc folded)

    int i = beg;
    for (; i + 16 <= end; i += 16) {
        int base = i + 4 * g;
        int r0 = sorted_r[base + 0];
        int r1 = sorted_r[base + 1];
        int r2 = sorted_r[base + 2];
        int r3 = sorted_r[base + 3];
        uint4 u0 = hp[(size_t)r0 * 16 + sub];
        uint4 u1 = hp[(size_t)r1 * 16 + sub];
        uint4 u2 = hp[(size_t)r2 * 16 + sub];
        uint4 u3 = hp[(size_t)r3 * 16 + sub];
        accum(u0); accum(u1); accum(u2); accum(u3);
    }
    for (int idx = i + g; idx < end; idx += 4) {
        accum(hp[(size_t)sorted_r[idx] * 16 + sub]);
    }
    a0 += __shfl_xor(a0, 32); a1 += __shfl_xor(a1, 32);
    a2 += __shfl_xor(a2, 32); a3 += __shfl_xor(a3, 32);
    a4 += __shfl_xor(a4, 32); a5 += __shfl_xor(a5, 32);
    a6 += __shfl_xor(a6, 32); a7 += __shfl_xor(a7, 32);
    a0 += __shfl_xor(a0, 16); a1 += __shfl_xor(a1, 16);
    a2 += __shfl_xor(a2, 16); a3 += __shfl_xor(a3, 16);
    a4 += __shfl_xor(a4, 16); a5 += __shfl_xor(a5, 16);
    a6 += __shfl_xor(a6, 16); a7 += __shfl_xor(a7, 16);
    if (g == 0) {
        float dc = dinv[c];
        __half2 h01 = __floats2half2_rn(a0 * dc, a1 * dc);
        __half2 h23 = __floats2half2_rn(a2 * dc, a3 * dc);
        __half2 h45 = __floats2half2_rn(a4 * dc, a5 * dc);
        __half2 h67 = __floats2half2_rn(a6 * dc, a7 * dc);
        uint4 o;
        o.x = *(unsigned int*)&h01; o.y = *(unsigned int*)&h23;
        o.z = *(unsigned int*)&h45; o.w = *(unsigned int*)&h67;
        ((uint4*)dst)[(size_t)c * 16 + sub] = o;
    }
}

// --------------------------------------------- pooling stage 1: partial sums
__global__ __launch_bounds__(256) void pool_partial(const __half* __restrict__ h,
                                                    const int* __restrict__ batch,
                                                    float* __restrict__ partials, int N) {
    int g = blockIdx.x >> 3, part8 = blockIdx.x & 7;
    int t = threadIdx.x, cp = t & 63, rp = t >> 6;
    int lo = 0, hi = N;
    while (lo < hi) { int m = (lo + hi) >> 1; if (batch[m] < g) lo = m + 1; else hi = m; }
    int beg = lo;
    lo = beg; hi = N;
    while (lo < hi) { int m = (lo + hi) >> 1; if (batch[m] < g + 1) lo = m + 1; else hi = m; }
    int end = lo;
    const __half2* h2 = (const __half2*)h;
    float ax = 0.f, ay = 0.f;
    for (int i = beg + part8 * 4 + rp; i < end; i += 32) {
        float2 v = __half22float2(h2[(size_t)i * 64 + cp]);
        ax += v.x; ay += v.y;
    }
    __shared__ float px[4][64], py[4][64];
    px[rp][cp] = ax; py[rp][cp] = ay;
    __syncthreads();
    if (rp == 0) {
        float sx = px[0][cp] + px[1][cp] + px[2][cp] + px[3][cp];
        float sy = py[0][cp] + py[1][cp] + py[2][cp] + py[3][cp];
        partials[(size_t)blockIdx.x * 128 + cp * 2]     = sx;
        partials[(size_t)blockIdx.x * 128 + cp * 2 + 1] = sy;
    }
}

// ------------------------------------------------- pooling stage 2 + MLP head
__global__ __launch_bounds__(128) void head_kernel(const float* __restrict__ partials,
                                                   const int* __restrict__ batch,
                                                   const float* __restrict__ b4,
                                                   const float* __restrict__ Wd1,
                                                   const float* __restrict__ bd1,
                                                   const float* __restrict__ Wd2,
                                                   const float* __restrict__ bd2,
                                                   const float* __restrict__ Wo,
                                                   const float* __restrict__ bo,
                                                   float* __restrict__ out, int N) {
    int g = blockIdx.x;
    int j = threadIdx.x;
    __shared__ float sA[128], sB[128], red[128];
    int lo = 0, hi = N;
    while (lo < hi) { int m = (lo + hi) >> 1; if (batch[m] < g) lo = m + 1; else hi = m; }
    int beg = lo;
    lo = beg; hi = N;
    while (lo < hi) { int m = (lo + hi) >> 1; if (batch[m] < g + 1) lo = m + 1; else hi = m; }
    int cnt = lo - beg;
    float s = 0.f;
#pragma unroll
    for (int p = 0; p < 8; ++p) s += partials[(size_t)(g * 8 + p) * 128 + j];
    sA[j] = (cnt > 0) ? s / (float)cnt + b4[j] : 0.f;
    __syncthreads();
    float a = bd1[j];
#pragma unroll 4
    for (int k = 0; k < 128; ++k) a += sA[k] * Wd1[k * HIDDEN + j];
    sB[j] = fmaxf(a, 0.f);
    __syncthreads();
    a = bd2[j];
#pragma unroll 4
    for (int k = 0; k < 128; ++k) a += sB[k] * Wd2[k * HIDDEN + j];
    red[j] = fmaxf(a, 0.f) * Wo[j];
    __syncthreads();
    for (int d = 64; d > 0; d >>= 1) {
        if (j < d) red[j] += red[j + d];
        __syncthreads();
    }
    if (j == 0) out[g] = red[0] + bo[0];
}

// ============================================================================
extern "C" void kernel_launch(void* const* d_in, const int* in_sizes, int n_in,
                              void* d_out, int out_size, void* d_ws, size_t ws_size,
                              hipStream_t stream) {
    const float* x   = (const float*)d_in[0];
    const int*   ei  = (const int*)d_in[1];
    const int*   bat = (const int*)d_in[2];
    const float* W1  = (const float*)d_in[3];
    const float* b1  = (const float*)d_in[4];
    const float* W2  = (const float*)d_in[5];
    const float* b2  = (const float*)d_in[6];
    const float* W4  = (const float*)d_in[7];
    const float* b4  = (const float*)d_in[8];
    const float* Wd1 = (const float*)d_in[9];
    const float* bd1 = (const float*)d_in[10];
    const float* Wd2 = (const float*)d_in[11];
    const float* bd2 = (const float*)d_in[12];
    const float* Wo  = (const float*)d_in[13];
    const float* bo  = (const float*)d_in[14];
    float* out = (float*)d_out;

    const int N = in_sizes[0] / 11;
    const int E = in_sizes[1] / 2;
    const int* row = ei;
    const int* col = ei + E;
    const int B = (N + (1 << BSHIFT) - 1) >> BSHIFT;   // #buckets

    size_t off = 0;
    auto carve = [&](size_t bytes) {
        void* p = (char*)d_ws + off;
        off += (bytes + 255) & ~(size_t)255;
        return p;
    };
    __half* bufHA    = (__half*)carve((size_t)N * HIDDEN * 2);
    __half* bufHB    = (__half*)carve((size_t)N * HIDDEN * 2);
    __half* xp       = (__half*)carve((size_t)N * 16 * 2);
    float*  aggx     = (float*)carve((size_t)N * 16 * 4);
    int*    deg      = (int*)carve((size_t)N * 4);
    int*    offsets  = (int*)carve((size_t)(N + 1) * 4);
    int*    cursor   = (int*)carve((size_t)N * 4);
    float*  dinv     = (float*)carve((size_t)N * 4);
    int*    sorted_r = (int*)carve((size_t)E * 4);
    int2*   pairs    = (int2*)carve((size_t)E * 8);
    int*    gcur     = (int*)carve((size_t)512 * 4);
    int*    bsums    = (int*)carve((size_t)1024 * 4);
    float*  partials = (float*)carve((size_t)128 * 8 * 128 * 4);
    __half* packW2   = (__half*)carve((size_t)(32768 + 128) * 2);
    __half* packW4   = (__half*)carve((size_t)(32768 + 128) * 2);
    (void)ws_size; (void)n_in; (void)out_size;

    // ---- build CSR (reused by all 3 layers)
    hipMemsetAsync(deg, 0, (size_t)N * 4, stream);
    count_kernel<<<(E + 255) / 256, 256, 0, stream>>>(col, deg, E);
    int scanBlocks = (N + 1023) / 1024;
    scan_blocksums<<<scanBlocks, 256, 0, stream>>>(deg, bsums, N);
    scan_write<<<scanBlocks, 256, 0, stream>>>(deg, bsums, offsets, cursor, dinv, N, E);
    init_gcur<<<2, 256, 0, stream>>>(offsets, gcur, N);
    fill_pass1<<<(E + CHUNK - 1) / CHUNK, 256, 0, stream>>>(row, col, gcur, pairs, E);
    fill_pass2<<<B, 256, 0, stream>>>(pairs, offsets, cursor, sorted_r, N);

    // ---- pack weights for MFMA (independent of CSR)
    pack_w<<<8, 256, 0, stream>>>(W2, b1, packW2);
    pack_w<<<8, 256, 0, stream>>>(W4, b2, packW4);

    int aggBlocks  = (N + 3) / 4;
    int mfmaBlocks = (N + 127) / 128;

    // ---- layer 1: aggregate dinv-folded fp16 input, then GEMM (linearity)
    pad_x<<<(N * 16 + 255) / 256, 256, 0, stream>>>(x, dinv, xp, N);
    agg16<<<aggBlocks, 256, 0, stream>>>(xp, aggx, offsets, sorted_r, dinv, N);
    gemm_in_agg<<<(N + 1) / 2, 256, 0, stream>>>(aggx, W1, bufHA, N);
    // ---- layer 2 (MFMA GEMM: relu(h1+b1)@W2, dinv folded into output)
    gemm_mfma<<<mfmaBlocks, 256, 0, stream>>>(bufHA, packW2, dinv, bufHB, N);
    agg128h<<<aggBlocks, 256, 0, stream>>>(bufHB, bufHA, offsets, sorted_r, dinv, N);
    // ---- layer 3
    gemm_mfma<<<mfmaBlocks, 256, 0, stream>>>(bufHA, packW4, dinv, bufHB, N);
    agg128h<<<aggBlocks, 256, 0, stream>>>(bufHB, bufHA, offsets, sorted_r, dinv, N);
    // ---- pool + head
    pool_partial<<<128 * 8, 256, 0, stream>>>(bufHA, bat, partials, N);
    head_kernel<<<128, 128, 0, stream>>>(partials, bat, b4, Wd1, bd1, Wd2, bd2,
                                         Wo, bo, out, N);
}

// Round 10
// 340.831 us; speedup vs baseline: 1.7152x; 1.2460x over previous
//
#include <hip/hip_runtime.h>
#include <hip/hip_fp16.h>

#define HIDDEN 128
#define BSHIFT 8          // bucket = 256 destination nodes
#define BMASK 255
#define CHUNK 6144        // edges per fill_bin block
#define BCAP 6144         // per-bucket capacity in ptmp (mean 4096, 32 sigma)

typedef _Float16 h8 __attribute__((ext_vector_type(8)));
typedef float f4x __attribute__((ext_vector_type(4)));

// ----------------- fill pass 1: LDS-bin edges into bucket-strided temp array
__global__ __launch_bounds__(256) void fill_bin(const int* __restrict__ row,
                                                const int* __restrict__ col,
                                                int* __restrict__ bcnt,
                                                int2* __restrict__ ptmp, int E) {
    __shared__ int cnt[512], start[512], place[512], gbase[512];
    __shared__ int ssum[256];
    __shared__ int2 stage[CHUNK];
    int t = threadIdx.x;
    int e0 = blockIdx.x * CHUNK;
    int e1 = min(e0 + CHUNK, E);
    cnt[t] = 0; cnt[t + 256] = 0;
    __syncthreads();
    // count buckets in this chunk
    for (int e = e0 + t; e < e1; e += 256)
        atomicAdd(&cnt[col[e] >> BSHIFT], 1);
    __syncthreads();
    // exclusive scan of 512 counters (pairwise + Hillis-Steele on 256)
    int s2 = cnt[2 * t] + cnt[2 * t + 1];
    ssum[t] = s2;
    __syncthreads();
    for (int d = 1; d < 256; d <<= 1) {
        int v = (t >= d) ? ssum[t - d] : 0;
        __syncthreads();
        ssum[t] += v;
        __syncthreads();
    }
    int excl = ssum[t] - s2;
    start[2 * t] = excl;
    start[2 * t + 1] = excl + cnt[2 * t];
    place[2 * t] = excl;
    place[2 * t + 1] = excl + cnt[2 * t];
    __syncthreads();
    // stage pairs bucket-contiguously in LDS
    for (int e = e0 + t; e < e1; e += 256) {
        int c = col[e], r = row[e];
        int slot = atomicAdd(&place[c >> BSHIFT], 1);
        stage[slot] = make_int2(r, c);
    }
    // reserve global space per bucket (cnt stable since count-phase sync)
    {
        int c0 = cnt[t], c1 = cnt[t + 256];
        if (c0 > 0) gbase[t] = atomicAdd(&bcnt[t], c0);
        if (c1 > 0) gbase[t + 256] = atomicAdd(&bcnt[t + 256], c1);
    }
    __syncthreads();
    // stream out into this bucket's strided segment
    int n = e1 - e0;
    for (int i = t; i < n; i += 256) {
        int2 p = stage[i];
        int b = p.y >> BSHIFT;
        ptmp[(size_t)b * BCAP + gbase[b] + (i - start[b])] = p;
    }
}

// --------------- tiny single-block scan of bucket totals -> global CSR bases
__global__ __launch_bounds__(512) void scan_buckets(const int* __restrict__ bcnt,
                                                    int* __restrict__ bbase, int NB) {
    __shared__ int s[512];
    int t = threadIdx.x;
    int v0 = (t < NB) ? bcnt[t] : 0;
    s[t] = v0;
    __syncthreads();
    for (int d = 1; d < 512; d <<= 1) {
        int v = (t >= d) ? s[t - d] : 0;
        __syncthreads();
        s[t] += v;
        __syncthreads();
    }
    bbase[t] = s[t] - v0;   // exclusive prefix
}

// ---- fill pass 2: one block per bucket — LDS degree histogram + local scatter
// produces offsets[], dinv[], sorted_r[] for its 256 nodes; no global atomics.
__global__ __launch_bounds__(256) void fill_scatter(const int2* __restrict__ ptmp,
                                                    const int* __restrict__ bcnt,
                                                    const int* __restrict__ bbase,
                                                    int* __restrict__ offsets,
                                                    float* __restrict__ dinv,
                                                    int* __restrict__ sorted_r,
                                                    int N, int E) {
    __shared__ int2 stage[BCAP];               // 48 KB
    __shared__ int cnt[256], loff[256], cur[256];
    int b = blockIdx.x, t = threadIdx.x;
    int m = bcnt[b];
    int base = bbase[b];
    int nbase = b << BSHIFT;
    cnt[t] = 0;
    __syncthreads();
    for (int i = t; i < m; i += 256) {
        int2 p = ptmp[(size_t)b * BCAP + i];
        stage[i] = p;
        atomicAdd(&cnt[p.y & BMASK], 1);
    }
    __syncthreads();
    int my = cnt[t];
    loff[t] = my;
    __syncthreads();
    for (int d = 1; d < 256; d <<= 1) {
        int v = (t >= d) ? loff[t - d] : 0;
        __syncthreads();
        loff[t] += v;
        __syncthreads();
    }
    int excl = loff[t] - my;
    cur[t] = excl;
    int node = nbase + t;
    if (node < N) {
        offsets[node] = base + excl;
        dinv[node] = rsqrtf((float)(my + 1));
    }
    if (b == gridDim.x - 1 && t == 0) offsets[N] = E;
    __syncthreads();
    for (int i = t; i < m; i += 256) {
        int2 p = stage[i];
        int slot = atomicAdd(&cur[p.y & BMASK], 1);
        sorted_r[base + slot] = p.x;   // contiguous ~16 KB region, block-local
    }
}

// ----------------- pad x [N,11] -> fp16 [N,16], folding dinv[i] into the row
__global__ __launch_bounds__(256) void pad_x(const float* __restrict__ x,
                                             const float* __restrict__ dinv,
                                             __half* __restrict__ xp, int N) {
    int q = blockIdx.x * 256 + threadIdx.x;
    if (q >= N * 16) return;
    int i = q >> 4, c = q & 15;
    float v = (c < 11) ? x[(size_t)i * 11 + c] * dinv[i] : 0.f;
    xp[q] = __float2half(v);
}

// -------------------- aggregate 16-ch dinv-folded input: aggx[c]=dc*(sum+self)
__global__ __launch_bounds__(256) void agg16(const __half* __restrict__ xp,
                                             float* __restrict__ aggx,
                                             const int* __restrict__ offsets,
                                             const int* __restrict__ sorted_r,
                                             const float* __restrict__ dinv, int N) {
    int wid  = (blockIdx.x * 256 + threadIdx.x) >> 6;
    int lane = threadIdx.x & 63;
    if (wid >= N) return;
    int c = wid;
    int g = lane >> 3, cp = lane & 7;
    int beg = offsets[c], end = offsets[c + 1];
    const __half2* xp2 = (const __half2*)xp;
    float ax = 0.f, ay = 0.f;
    if (g == 0) {
        float2 v = __half22float2(xp2[(size_t)c * 8 + cp]);   // self (dc folded)
        ax = v.x; ay = v.y;
    }
    for (int idx = beg + g; idx < end; idx += 8) {
        int r = sorted_r[idx];
        float2 v = __half22float2(xp2[(size_t)r * 8 + cp]);
        ax += v.x; ay += v.y;
    }
    ax += __shfl_xor(ax, 32); ay += __shfl_xor(ay, 32);
    ax += __shfl_xor(ax, 16); ay += __shfl_xor(ay, 16);
    ax += __shfl_xor(ax, 8);  ay += __shfl_xor(ay, 8);
    if (lane < 8) {
        float dc = dinv[c];
        aggx[(size_t)c * 16 + cp * 2]     = ax * dc;
        aggx[(size_t)c * 16 + cp * 2 + 1] = ay * dc;
    }
}

// ---------------------------- GEMM: h1 = aggx[:, :11] @ W1 -> fp16 (conv1 out)
__global__ __launch_bounds__(256) void gemm_in_agg(const float* __restrict__ aggx,
                                                   const float* __restrict__ W1,
                                                   __half* __restrict__ out, int N) {
    int i = blockIdx.x * 2 + (threadIdx.x >> 7);
    int j = threadIdx.x & 127;
    if (i >= N) return;
    float acc = 0.f;
#pragma unroll
    for (int c = 0; c < 11; ++c) acc += aggx[(size_t)i * 16 + c] * W1[c * HIDDEN + j];
    out[(size_t)i * HIDDEN + j] = __float2half(acc);
}

// ---------------- pack W [128][128] fp32 -> MFMA B-fragment order, hi|lo fp16
__global__ __launch_bounds__(256) void pack_w(const float* __restrict__ W,
                                              const float* __restrict__ bias,
                                              __half* __restrict__ packed) {
    int q = blockIdx.x * 256 + threadIdx.x;
    if (q < 2048) {
        int s = q >> 9, rem = q & 511, ct = rem >> 6, l = rem & 63;
        int b = l >> 4, n = l & 15;
        __half hi8[8], lo8[8];
#pragma unroll
        for (int i = 0; i < 8; ++i) {
            float w = W[(s * 32 + b * 8 + i) * HIDDEN + ct * 16 + n];
            __half h = __float2half(w);
            hi8[i] = h;
            lo8[i] = __float2half(w - __half2float(h));
        }
        *(uint4*)(packed + (size_t)q * 8)         = *(uint4*)hi8;
        *(uint4*)(packed + 16384 + (size_t)q * 8) = *(uint4*)lo8;
    }
    if (q < 128) packed[32768 + q] = __float2half(bias[q]);
}

// ------------- MFMA GEMM: out = fp16( dinv[i] * (relu(H+b) @ (Whi+Wlo)) )
__global__ __launch_bounds__(256) void gemm_mfma(const __half* __restrict__ H,
                                                 const __half* __restrict__ packed,
                                                 const float* __restrict__ dinv,
                                                 __half* __restrict__ out, int N) {
    __shared__ __half Wl[32768];   // hi | lo, 64 KB
    for (int q = threadIdx.x; q < 4096; q += 256)
        ((uint4*)Wl)[q] = ((const uint4*)packed)[q];
    int l = threadIdx.x & 63, wv = threadIdx.x >> 6;
    int m = l & 15, b = l >> 4;
    const __half* bias_h = packed + 32768;
    __syncthreads();

    f4x acc[2][8];
#pragma unroll
    for (int t = 0; t < 2; ++t)
#pragma unroll
        for (int ct = 0; ct < 8; ++ct) acc[t][ct] = (f4x){0.f, 0.f, 0.f, 0.f};

    int rowA0 = blockIdx.x * 128 + wv * 32 + m;

#pragma unroll
    for (int s = 0; s < 4; ++s) {
        uint4 bv = *(const uint4*)(bias_h + s * 32 + b * 8);
        __half2* bh = (__half2*)&bv;
        h8 a[2];
#pragma unroll
        for (int t = 0; t < 2; ++t) {
            int row = rowA0 + t * 16;
            uint4 av = make_uint4(0u, 0u, 0u, 0u);
            if (row < N) av = *(const uint4*)(H + (size_t)row * HIDDEN + s * 32 + b * 8);
            __half2* ah = (__half2*)&av;
#pragma unroll
            for (int p = 0; p < 4; ++p) {
                float2 f  = __half22float2(ah[p]);
                float2 bf = __half22float2(bh[p]);
                ah[p] = __floats2half2_rn(fmaxf(f.x + bf.x, 0.f), fmaxf(f.y + bf.y, 0.f));
            }
            a[t] = *(h8*)&av;
        }
#pragma unroll
        for (int ct = 0; ct < 8; ++ct) {
            h8 whi = *(h8*)&Wl[((s * 8 + ct) * 64 + l) * 8];
            h8 wlo = *(h8*)&Wl[16384 + ((s * 8 + ct) * 64 + l) * 8];
#pragma unroll
            for (int t = 0; t < 2; ++t) {
                acc[t][ct] = __builtin_amdgcn_mfma_f32_16x16x32_f16(a[t], whi, acc[t][ct], 0, 0, 0);
                acc[t][ct] = __builtin_amdgcn_mfma_f32_16x16x32_f16(a[t], wlo, acc[t][ct], 0, 0, 0);
            }
        }
    }
#pragma unroll
    for (int t = 0; t < 2; ++t) {
        int rbase = blockIdx.x * 128 + wv * 32 + t * 16 + b * 4;
#pragma unroll
        for (int i = 0; i < 4; ++i) {
            int row = rbase + i;
            if (row < N) {
                float dv = dinv[row];
#pragma unroll
                for (int ct = 0; ct < 8; ++ct)
                    out[(size_t)row * HIDDEN + ct * 16 + m] = __float2half(acc[t][ct][i] * dv);
            }
        }
    }
}

// -------- aggregation 128ch fp16, no edge weights (dinv folded into features)
__global__ __launch_bounds__(256) void agg128h(const __half* __restrict__ src,
                                               __half* __restrict__ dst,
                                               const int* __restrict__ offsets,
                                               const int* __restrict__ sorted_r,
                                               const float* __restrict__ dinv, int N) {
    int wid  = (blockIdx.x * 256 + threadIdx.x) >> 6;
    int lane = threadIdx.x & 63;
    if (wid >= N) return;
    int c = wid;
    int beg = offsets[c], end = offsets[c + 1];
    int g = lane >> 4, sub = lane & 15;
    const uint4* hp = (const uint4*)src;
    float a0=0.f,a1=0.f,a2=0.f,a3=0.f,a4=0.f,a5=0.f,a6=0.f,a7=0.f;

    auto accum = [&](uint4 u) {
        __half2 p0 = *(__half2*)&u.x, p1 = *(__half2*)&u.y;
        __half2 p2 = *(__half2*)&u.z, p3 = *(__half2*)&u.w;
        float2 f0 = __half22float2(p0), f1 = __half22float2(p1);
        float2 f2 = __half22float2(p2), f3 = __half22float2(p3);
        a0 += f0.x; a1 += f0.y; a2 += f1.x; a3 += f1.y;
        a4 += f2.x; a5 += f2.y; a6 += f3.x; a7 += f3.y;
    };

    if (g == 0) accum(hp[(size_t)c * 16 + sub]);   // self loop (dc folded)

    int i = beg;
    for (; i + 16 <= end; i += 16) {
        int base = i + 4 * g;
        int r0 = sorted_r[base + 0];
        int r1 = sorted_r[base + 1];
        int r2 = sorted_r[base + 2];
        int r3 = sorted_r[base + 3];
        uint4 u0 = hp[(size_t)r0 * 16 + sub];
        uint4 u1 = hp[(size_t)r1 * 16 + sub];
        uint4 u2 = hp[(size_t)r2 * 16 + sub];
        uint4 u3 = hp[(size_t)r3 * 16 + sub];
        accum(u0); accum(u1); accum(u2); accum(u3);
    }
    for (int idx = i + g; idx < end; idx += 4) {
        accum(hp[(size_t)sorted_r[idx] * 16 + sub]);
    }
    a0 += __shfl_xor(a0, 32); a1 += __shfl_xor(a1, 32);
    a2 += __shfl_xor(a2, 32); a3 += __shfl_xor(a3, 32);
    a4 += __shfl_xor(a4, 32); a5 += __shfl_xor(a5, 32);
    a6 += __shfl_xor(a6, 32); a7 += __shfl_xor(a7, 32);
    a0 += __shfl_xor(a0, 16); a1 += __shfl_xor(a1, 16);
    a2 += __shfl_xor(a2, 16); a3 += __shfl_xor(a3, 16);
    a4 += __shfl_xor(a4, 16); a5 += __shfl_xor(a5, 16);
    a6 += __shfl_xor(a6, 16); a7 += __shfl_xor(a7, 16);
    if (g == 0) {
        float dc = dinv[c];
        __half2 h01 = __floats2half2_rn(a0 * dc, a1 * dc);
        __half2 h23 = __floats2half2_rn(a2 * dc, a3 * dc);
        __half2 h45 = __floats2half2_rn(a4 * dc, a5 * dc);
        __half2 h67 = __floats2half2_rn(a6 * dc, a7 * dc);
        uint4 o;
        o.x = *(unsigned int*)&h01; o.y = *(unsigned int*)&h23;
        o.z = *(unsigned int*)&h45; o.w = *(unsigned int*)&h67;
        ((uint4*)dst)[(size_t)c * 16 + sub] = o;
    }
}

// --------------------------------------------- pooling stage 1: partial sums
__global__ __launch_bounds__(256) void pool_partial(const __half* __restrict__ h,
                                                    const int* __restrict__ batch,
                                                    float* __restrict__ partials, int N) {
    int g = blockIdx.x >> 3, part8 = blockIdx.x & 7;
    int t = threadIdx.x, cp = t & 63, rp = t >> 6;
    int lo = 0, hi = N;
    while (lo < hi) { int m = (lo + hi) >> 1; if (batch[m] < g) lo = m + 1; else hi = m; }
    int beg = lo;
    lo = beg; hi = N;
    while (lo < hi) { int m = (lo + hi) >> 1; if (batch[m] < g + 1) lo = m + 1; else hi = m; }
    int end = lo;
    const __half2* h2 = (const __half2*)h;
    float ax = 0.f, ay = 0.f;
    for (int i = beg + part8 * 4 + rp; i < end; i += 32) {
        float2 v = __half22float2(h2[(size_t)i * 64 + cp]);
        ax += v.x; ay += v.y;
    }
    __shared__ float px[4][64], py[4][64];
    px[rp][cp] = ax; py[rp][cp] = ay;
    __syncthreads();
    if (rp == 0) {
        float sx = px[0][cp] + px[1][cp] + px[2][cp] + px[3][cp];
        float sy = py[0][cp] + py[1][cp] + py[2][cp] + py[3][cp];
        partials[(size_t)blockIdx.x * 128 + cp * 2]     = sx;
        partials[(size_t)blockIdx.x * 128 + cp * 2 + 1] = sy;
    }
}

// ------------------------------------------------- pooling stage 2 + MLP head
__global__ __launch_bounds__(128) void head_kernel(const float* __restrict__ partials,
                                                   const int* __restrict__ batch,
                                                   const float* __restrict__ b4,
                                                   const float* __restrict__ Wd1,
                                                   const float* __restrict__ bd1,
                                                   const float* __restrict__ Wd2,
                                                   const float* __restrict__ bd2,
                                                   const float* __restrict__ Wo,
                                                   const float* __restrict__ bo,
                                                   float* __restrict__ out, int N) {
    int g = blockIdx.x;
    int j = threadIdx.x;
    __shared__ float sA[128], sB[128], red[128];
    int lo = 0, hi = N;
    while (lo < hi) { int m = (lo + hi) >> 1; if (batch[m] < g) lo = m + 1; else hi = m; }
    int beg = lo;
    lo = beg; hi = N;
    while (lo < hi) { int m = (lo + hi) >> 1; if (batch[m] < g + 1) lo = m + 1; else hi = m; }
    int cnt = lo - beg;
    float s = 0.f;
#pragma unroll
    for (int p = 0; p < 8; ++p) s += partials[(size_t)(g * 8 + p) * 128 + j];
    sA[j] = (cnt > 0) ? s / (float)cnt + b4[j] : 0.f;
    __syncthreads();
    float a = bd1[j];
#pragma unroll 4
    for (int k = 0; k < 128; ++k) a += sA[k] * Wd1[k * HIDDEN + j];
    sB[j] = fmaxf(a, 0.f);
    __syncthreads();
    a = bd2[j];
#pragma unroll 4
    for (int k = 0; k < 128; ++k) a += sB[k] * Wd2[k * HIDDEN + j];
    red[j] = fmaxf(a, 0.f) * Wo[j];
    __syncthreads();
    for (int d = 64; d > 0; d >>= 1) {
        if (j < d) red[j] += red[j + d];
        __syncthreads();
    }
    if (j == 0) out[g] = red[0] + bo[0];
}

// ============================================================================
extern "C" void kernel_launch(void* const* d_in, const int* in_sizes, int n_in,
                              void* d_out, int out_size, void* d_ws, size_t ws_size,
                              hipStream_t stream) {
    const float* x   = (const float*)d_in[0];
    const int*   ei  = (const int*)d_in[1];
    const int*   bat = (const int*)d_in[2];
    const float* W1  = (const float*)d_in[3];
    const float* b1  = (const float*)d_in[4];
    const float* W2  = (const float*)d_in[5];
    const float* b2  = (const float*)d_in[6];
    const float* W4  = (const float*)d_in[7];
    const float* b4  = (const float*)d_in[8];
    const float* Wd1 = (const float*)d_in[9];
    const float* bd1 = (const float*)d_in[10];
    const float* Wd2 = (const float*)d_in[11];
    const float* bd2 = (const float*)d_in[12];
    const float* Wo  = (const float*)d_in[13];
    const float* bo  = (const float*)d_in[14];
    float* out = (float*)d_out;

    const int N = in_sizes[0] / 11;
    const int E = in_sizes[1] / 2;
    const int* row = ei;
    const int* col = ei + E;
    const int B = (N + (1 << BSHIFT) - 1) >> BSHIFT;   // #buckets

    size_t off = 0;
    auto carve = [&](size_t bytes) {
        void* p = (char*)d_ws + off;
        off += (bytes + 255) & ~(size_t)255;
        return p;
    };
    __half* bufHA    = (__half*)carve((size_t)N * HIDDEN * 2);
    __half* bufHB    = (__half*)carve((size_t)N * HIDDEN * 2);
    __half* xp       = (__half*)carve((size_t)N * 16 * 2);
    float*  aggx     = (float*)carve((size_t)N * 16 * 4);
    int*    offsets  = (int*)carve((size_t)(N + 1) * 4);
    float*  dinv     = (float*)carve((size_t)N * 4);
    int*    sorted_r = (int*)carve((size_t)E * 4);
    int*    bcnt     = (int*)carve((size_t)512 * 4);
    int*    bbase    = (int*)carve((size_t)512 * 4);
    float*  partials = (float*)carve((size_t)128 * 8 * 128 * 4);
    __half* packW2   = (__half*)carve((size_t)(32768 + 128) * 2);
    __half* packW4   = (__half*)carve((size_t)(32768 + 128) * 2);
    // ptmp aliases bufHA (dead until gemm_in_agg; B*BCAP*8 = 19.2 MB < 25.6 MB)
    int2* ptmp = (int2*)bufHA;
    (void)ws_size; (void)n_in; (void)out_size;

    // ---- build CSR: bucket-binned, no global histogram / scatter atomics
    hipMemsetAsync(bcnt, 0, (size_t)512 * 4, stream);
    fill_bin<<<(E + CHUNK - 1) / CHUNK, 256, 0, stream>>>(row, col, bcnt, ptmp, E);
    scan_buckets<<<1, 512, 0, stream>>>(bcnt, bbase, B);
    fill_scatter<<<B, 256, 0, stream>>>(ptmp, bcnt, bbase, offsets, dinv,
                                        sorted_r, N, E);

    // ---- pack weights for MFMA (independent of CSR)
    pack_w<<<8, 256, 0, stream>>>(W2, b1, packW2);
    pack_w<<<8, 256, 0, stream>>>(W4, b2, packW4);

    int aggBlocks  = (N + 3) / 4;
    int mfmaBlocks = (N + 127) / 128;

    // ---- layer 1: aggregate dinv-folded fp16 input, then GEMM (linearity)
    pad_x<<<(N * 16 + 255) / 256, 256, 0, stream>>>(x, dinv, xp, N);
    agg16<<<aggBlocks, 256, 0, stream>>>(xp, aggx, offsets, sorted_r, dinv, N);
    gemm_in_agg<<<(N + 1) / 2, 256, 0, stream>>>(aggx, W1, bufHA, N);
    // ---- layer 2 (MFMA GEMM: relu(h1+b1)@W2, dinv folded into output)
    gemm_mfma<<<mfmaBlocks, 256, 0, stream>>>(bufHA, packW2, dinv, bufHB, N);
    agg128h<<<aggBlocks, 256, 0, stream>>>(bufHB, bufHA, offsets, sorted_r, dinv, N);
    // ---- layer 3
    gemm_mfma<<<mfmaBlocks, 256, 0, stream>>>(bufHA, packW4, dinv, bufHB, N);
    agg128h<<<aggBlocks, 256, 0, stream>>>(bufHB, bufHA, offsets, sorted_r, dinv, N);
    // ---- pool + head
    pool_partial<<<128 * 8, 256, 0, stream>>>(bufHA, bat, partials, N);
    head_kernel<<<128, 128, 0, stream>>>(partials, bat, b4, Wd1, bd1, Wd2, bd2,
                                         Wo, bo, out, N);
}

// Round 11
// 333.645 us; speedup vs baseline: 1.7522x; 1.0215x over previous
//
#include <hip/hip_runtime.h>
#include <hip/hip_fp16.h>

#define HIDDEN 128
#define BSHIFT 8          // bucket = 256 destination nodes
#define BMASK 255
#define CHUNK 4096        // edges per fill_bin block (40 KB LDS -> 4 blocks/CU)
#define BCAP 6144         // per-bucket capacity in ptmp (mean 4096, 32 sigma)

typedef _Float16 h8 __attribute__((ext_vector_type(8)));
typedef float f4x __attribute__((ext_vector_type(4)));

// ----------------- fill pass 1: LDS-bin edges into bucket-strided temp array
__global__ __launch_bounds__(256) void fill_bin(const int* __restrict__ row,
                                                const int* __restrict__ col,
                                                int* __restrict__ bcnt,
                                                int2* __restrict__ ptmp, int E) {
    __shared__ int cnt[512], start[512], place[512], gbase[512];
    __shared__ int ssum[256];
    __shared__ int2 stage[CHUNK];
    int t = threadIdx.x;
    int e0 = blockIdx.x * CHUNK;
    int e1 = min(e0 + CHUNK, E);
    cnt[t] = 0; cnt[t + 256] = 0;
    __syncthreads();
    for (int e = e0 + t; e < e1; e += 256)
        atomicAdd(&cnt[col[e] >> BSHIFT], 1);
    __syncthreads();
    int s2 = cnt[2 * t] + cnt[2 * t + 1];
    ssum[t] = s2;
    __syncthreads();
    for (int d = 1; d < 256; d <<= 1) {
        int v = (t >= d) ? ssum[t - d] : 0;
        __syncthreads();
        ssum[t] += v;
        __syncthreads();
    }
    int excl = ssum[t] - s2;
    start[2 * t] = excl;
    start[2 * t + 1] = excl + cnt[2 * t];
    place[2 * t] = excl;
    place[2 * t + 1] = excl + cnt[2 * t];
    __syncthreads();
    for (int e = e0 + t; e < e1; e += 256) {
        int c = col[e], r = row[e];
        int slot = atomicAdd(&place[c >> BSHIFT], 1);
        stage[slot] = make_int2(r, c);
    }
    {
        int c0 = cnt[t], c1 = cnt[t + 256];
        if (c0 > 0) gbase[t] = atomicAdd(&bcnt[t], c0);
        if (c1 > 0) gbase[t + 256] = atomicAdd(&bcnt[t + 256], c1);
    }
    __syncthreads();
    int n = e1 - e0;
    for (int i = t; i < n; i += 256) {
        int2 p = stage[i];
        int b = p.y >> BSHIFT;
        ptmp[(size_t)b * BCAP + gbase[b] + (i - start[b])] = p;
    }
}

// --------------- tiny single-block scan of bucket totals -> global CSR bases
__global__ __launch_bounds__(512) void scan_buckets(const int* __restrict__ bcnt,
                                                    int* __restrict__ bbase, int NB) {
    __shared__ int s[512];
    int t = threadIdx.x;
    int v0 = (t < NB) ? bcnt[t] : 0;
    s[t] = v0;
    __syncthreads();
    for (int d = 1; d < 512; d <<= 1) {
        int v = (t >= d) ? s[t - d] : 0;
        __syncthreads();
        s[t] += v;
        __syncthreads();
    }
    bbase[t] = s[t] - v0;   // exclusive prefix
}

// ---- fill pass 2: one block per bucket — LDS degree histogram + local scatter
__global__ __launch_bounds__(256) void fill_scatter(const int2* __restrict__ ptmp,
                                                    const int* __restrict__ bcnt,
                                                    const int* __restrict__ bbase,
                                                    int* __restrict__ offsets,
                                                    float* __restrict__ dinv,
                                                    int* __restrict__ sorted_r,
                                                    int N, int E) {
    __shared__ int2 stage[BCAP];               // 48 KB
    __shared__ int cnt[256], loff[256], cur[256];
    int b = blockIdx.x, t = threadIdx.x;
    int m = bcnt[b];
    int base = bbase[b];
    int nbase = b << BSHIFT;
    cnt[t] = 0;
    __syncthreads();
    for (int i = t; i < m; i += 256) {
        int2 p = ptmp[(size_t)b * BCAP + i];
        stage[i] = p;
        atomicAdd(&cnt[p.y & BMASK], 1);
    }
    __syncthreads();
    int my = cnt[t];
    loff[t] = my;
    __syncthreads();
    for (int d = 1; d < 256; d <<= 1) {
        int v = (t >= d) ? loff[t - d] : 0;
        __syncthreads();
        loff[t] += v;
        __syncthreads();
    }
    int excl = loff[t] - my;
    cur[t] = excl;
    int node = nbase + t;
    if (node < N) {
        offsets[node] = base + excl;
        dinv[node] = rsqrtf((float)(my + 1));
    }
    if (b == gridDim.x - 1 && t == 0) offsets[N] = E;
    __syncthreads();
    for (int i = t; i < m; i += 256) {
        int2 p = stage[i];
        int slot = atomicAdd(&cur[p.y & BMASK], 1);
        sorted_r[base + slot] = p.x;   // contiguous ~16 KB region, block-local
    }
}

// ----------------- pad x [N,11] -> fp16 [N,16], folding dinv[i] into the row
__global__ __launch_bounds__(256) void pad_x(const float* __restrict__ x,
                                             const float* __restrict__ dinv,
                                             __half* __restrict__ xp, int N) {
    int q = blockIdx.x * 256 + threadIdx.x;
    if (q >= N * 16) return;
    int i = q >> 4, c = q & 15;
    float v = (c < 11) ? x[(size_t)i * 11 + c] * dinv[i] : 0.f;
    xp[q] = __float2half(v);
}

// -------------------- aggregate 16-ch dinv-folded input: aggx[c]=dc*(sum+self)
__global__ __launch_bounds__(256) void agg16(const __half* __restrict__ xp,
                                             float* __restrict__ aggx,
                                             const int* __restrict__ offsets,
                                             const int* __restrict__ sorted_r,
                                             const float* __restrict__ dinv, int N) {
    int wid  = (blockIdx.x * 256 + threadIdx.x) >> 6;
    int lane = threadIdx.x & 63;
    if (wid >= N) return;
    int c = wid;
    int g = lane >> 3, cp = lane & 7;
    int beg = offsets[c], end = offsets[c + 1];
    const __half2* xp2 = (const __half2*)xp;
    float ax = 0.f, ay = 0.f;
    if (g == 0) {
        float2 v = __half22float2(xp2[(size_t)c * 8 + cp]);   // self (dc folded)
        ax = v.x; ay = v.y;
    }
    for (int idx = beg + g; idx < end; idx += 8) {
        int r = sorted_r[idx];
        float2 v = __half22float2(xp2[(size_t)r * 8 + cp]);
        ax += v.x; ay += v.y;
    }
    ax += __shfl_xor(ax, 32); ay += __shfl_xor(ay, 32);
    ax += __shfl_xor(ax, 16); ay += __shfl_xor(ay, 16);
    ax += __shfl_xor(ax, 8);  ay += __shfl_xor(ay, 8);
    if (lane < 8) {
        float dc = dinv[c];
        aggx[(size_t)c * 16 + cp * 2]     = ax * dc;
        aggx[(size_t)c * 16 + cp * 2 + 1] = ay * dc;
    }
}

// ---------------------------- GEMM: h1 = aggx[:, :11] @ W1 -> fp16 (conv1 out)
__global__ __launch_bounds__(256) void gemm_in_agg(const float* __restrict__ aggx,
                                                   const float* __restrict__ W1,
                                                   __half* __restrict__ out, int N) {
    int i = blockIdx.x * 2 + (threadIdx.x >> 7);
    int j = threadIdx.x & 127;
    if (i >= N) return;
    float acc = 0.f;
#pragma unroll
    for (int c = 0; c < 11; ++c) acc += aggx[(size_t)i * 16 + c] * W1[c * HIDDEN + j];
    out[(size_t)i * HIDDEN + j] = __float2half(acc);
}

// ---------------- pack W [128][128] fp32 -> MFMA fragment order, hi|lo fp16
// entry q = ((s*8+ct)*64 + l), halves i: W[32s+8*(l>>4)+i][16ct+(l&15)]
// (fragment lane layout: l&15 = output-channel, l>>4 = k-octet)
__global__ __launch_bounds__(256) void pack_w(const float* __restrict__ W,
                                              const float* __restrict__ bias,
                                              __half* __restrict__ packed) {
    int q = blockIdx.x * 256 + threadIdx.x;
    if (q < 2048) {
        int s = q >> 9, rem = q & 511, ct = rem >> 6, l = rem & 63;
        int b = l >> 4, n = l & 15;
        __half hi8[8], lo8[8];
#pragma unroll
        for (int i = 0; i < 8; ++i) {
            float w = W[(s * 32 + b * 8 + i) * HIDDEN + ct * 16 + n];
            __half h = __float2half(w);
            hi8[i] = h;
            lo8[i] = __float2half(w - __half2float(h));
        }
        *(uint4*)(packed + (size_t)q * 8)         = *(uint4*)hi8;
        *(uint4*)(packed + 16384 + (size_t)q * 8) = *(uint4*)lo8;
    }
    if (q < 128) packed[32768 + q] = __float2half(bias[q]);
}

// ---- MFMA GEMM, register-resident W (swapped operands, no LDS):
// D[ch][node] = sum_k W[k][ch]*relu(H[node][k]+b[k]); out[node][ch]=D*dinv[node]
// wave owns 4 ch-tiles (cthalf); 32 W-frags (hi+lo) in VGPRs; grid-stride nodes.
__global__ __launch_bounds__(256, 2) void gemm_mfma(const __half* __restrict__ H,
                                                    const __half* __restrict__ packed,
                                                    const float* __restrict__ dinv,
                                                    __half* __restrict__ out,
                                                    int N, int ngroups) {
    int l = threadIdx.x & 63, wv = threadIdx.x >> 6;
    int cthalf = wv & 1;
    int n16 = l & 15, koct = l >> 4;
    h8 whi[4][4], wlo[4][4];
#pragma unroll
    for (int s = 0; s < 4; ++s)
#pragma unroll
        for (int mt = 0; mt < 4; ++mt) {
            int ct = cthalf * 4 + mt;
            whi[s][mt] = *(const h8*)(packed + (size_t)((s * 8 + ct) * 64 + l) * 8);
            wlo[s][mt] = *(const h8*)(packed + 16384 + (size_t)((s * 8 + ct) * 64 + l) * 8);
        }
    h8 biasf[4];
    const __half* bias_h = packed + 32768;
#pragma unroll
    for (int s = 0; s < 4; ++s)
        biasf[s] = *(const h8*)(bias_h + s * 32 + koct * 8);

    for (int g = blockIdx.x * 2 + (wv >> 1); g < ngroups; g += gridDim.x * 2) {
        int node = g * 16 + n16;
        bool ok = node < N;
        f4x acc[4];
#pragma unroll
        for (int mt = 0; mt < 4; ++mt) acc[mt] = (f4x){0.f, 0.f, 0.f, 0.f};
#pragma unroll
        for (int s = 0; s < 4; ++s) {
            uint4 bv = make_uint4(0u, 0u, 0u, 0u);
            if (ok) bv = *(const uint4*)(H + (size_t)node * HIDDEN + s * 32 + koct * 8);
            __half2* bh2 = (__half2*)&bv;
            const __half2* bb = (const __half2*)&biasf[s];
#pragma unroll
            for (int p = 0; p < 4; ++p) {
                float2 f  = __half22float2(bh2[p]);
                float2 bf = __half22float2(bb[p]);
                bh2[p] = __floats2half2_rn(fmaxf(f.x + bf.x, 0.f), fmaxf(f.y + bf.y, 0.f));
            }
            h8 bfrag = *(h8*)&bv;
#pragma unroll
            for (int mt = 0; mt < 4; ++mt) {
                acc[mt] = __builtin_amdgcn_mfma_f32_16x16x32_f16(whi[s][mt], bfrag, acc[mt], 0, 0, 0);
                acc[mt] = __builtin_amdgcn_mfma_f32_16x16x32_f16(wlo[s][mt], bfrag, acc[mt], 0, 0, 0);
            }
        }
        if (ok) {
            float dv = dinv[node];
#pragma unroll
            for (int mt = 0; mt < 4; ++mt) {
                int ch = (cthalf * 4 + mt) * 16 + koct * 4;   // D row = koct*4+i
                __half2 h01 = __floats2half2_rn(acc[mt][0] * dv, acc[mt][1] * dv);
                __half2 h23 = __floats2half2_rn(acc[mt][2] * dv, acc[mt][3] * dv);
                uint2 o;
                o.x = *(unsigned int*)&h01; o.y = *(unsigned int*)&h23;
                *(uint2*)(out + (size_t)node * HIDDEN + ch) = o;
            }
        }
    }
}

// -------- aggregation 128ch fp16, no edge weights (dinv folded into features)
__global__ __launch_bounds__(256) void agg128h(const __half* __restrict__ src,
                                               __half* __restrict__ dst,
                                               const int* __restrict__ offsets,
                                               const int* __restrict__ sorted_r,
                                               const float* __restrict__ dinv, int N) {
    int wid  = (blockIdx.x * 256 + threadIdx.x) >> 6;
    int lane = threadIdx.x & 63;
    if (wid >= N) return;
    int c = wid;
    int beg = offsets[c], end = offsets[c + 1];
    int g = lane >> 4, sub = lane & 15;
    const uint4* hp = (const uint4*)src;
    float a0=0.f,a1=0.f,a2=0.f,a3=0.f,a4=0.f,a5=0.f,a6=0.f,a7=0.f;

    auto accum = [&](uint4 u) {
        __half2 p0 = *(__half2*)&u.x, p1 = *(__half2*)&u.y;
        __half2 p2 = *(__half2*)&u.z, p3 = *(__half2*)&u.w;
        float2 f0 = __half22float2(p0), f1 = __half22float2(p1);
        float2 f2 = __half22float2(p2), f3 = __half22float2(p3);
        a0 += f0.x; a1 += f0.y; a2 += f1.x; a3 += f1.y;
        a4 += f2.x; a5 += f2.y; a6 += f3.x; a7 += f3.y;
    };

    if (g == 0) accum(hp[(size_t)c * 16 + sub]);   // self loop (dc folded)

    int i = beg;
    for (; i + 16 <= end; i += 16) {
        int base = i + 4 * g;
        int r0 = sorted_r[base + 0];
        int r1 = sorted_r[base + 1];
        int r2 = sorted_r[base + 2];
        int r3 = sorted_r[base + 3];
        uint4 u0 = hp[(size_t)r0 * 16 + sub];
        uint4 u1 = hp[(size_t)r1 * 16 + sub];
        uint4 u2 = hp[(size_t)r2 * 16 + sub];
        uint4 u3 = hp[(size_t)r3 * 16 + sub];
        accum(u0); accum(u1); accum(u2); accum(u3);
    }
    for (int idx = i + g; idx < end; idx += 4) {
        accum(hp[(size_t)sorted_r[idx] * 16 + sub]);
    }
    a0 += __shfl_xor(a0, 32); a1 += __shfl_xor(a1, 32);
    a2 += __shfl_xor(a2, 32); a3 += __shfl_xor(a3, 32);
    a4 += __shfl_xor(a4, 32); a5 += __shfl_xor(a5, 32);
    a6 += __shfl_xor(a6, 32); a7 += __shfl_xor(a7, 32);
    a0 += __shfl_xor(a0, 16); a1 += __shfl_xor(a1, 16);
    a2 += __shfl_xor(a2, 16); a3 += __shfl_xor(a3, 16);
    a4 += __shfl_xor(a4, 16); a5 += __shfl_xor(a5, 16);
    a6 += __shfl_xor(a6, 16); a7 += __shfl_xor(a7, 16);
    if (g == 0) {
        float dc = dinv[c];
        __half2 h01 = __floats2half2_rn(a0 * dc, a1 * dc);
        __half2 h23 = __floats2half2_rn(a2 * dc, a3 * dc);
        __half2 h45 = __floats2half2_rn(a4 * dc, a5 * dc);
        __half2 h67 = __floats2half2_rn(a6 * dc, a7 * dc);
        uint4 o;
        o.x = *(unsigned int*)&h01; o.y = *(unsigned int*)&h23;
        o.z = *(unsigned int*)&h45; o.w = *(unsigned int*)&h67;
        ((uint4*)dst)[(size_t)c * 16 + sub] = o;
    }
}

// --------------------------------------------- pooling stage 1: partial sums
__global__ __launch_bounds__(256) void pool_partial(const __half* __restrict__ h,
                                                    const int* __restrict__ batch,
                                                    float* __restrict__ partials, int N) {
    int g = blockIdx.x >> 3, part8 = blockIdx.x & 7;
    int t = threadIdx.x, cp = t & 63, rp = t >> 6;
    int lo = 0, hi = N;
    while (lo < hi) { int m = (lo + hi) >> 1; if (batch[m] < g) lo = m + 1; else hi = m; }
    int beg = lo;
    lo = beg; hi = N;
    while (lo < hi) { int m = (lo + hi) >> 1; if (batch[m] < g + 1) lo = m + 1; else hi = m; }
    int end = lo;
    const __half2* h2 = (const __half2*)h;
    float ax = 0.f, ay = 0.f;
    for (int i = beg + part8 * 4 + rp; i < end; i += 32) {
        float2 v = __half22float2(h2[(size_t)i * 64 + cp]);
        ax += v.x; ay += v.y;
    }
    __shared__ float px[4][64], py[4][64];
    px[rp][cp] = ax; py[rp][cp] = ay;
    __syncthreads();
    if (rp == 0) {
        float sx = px[0][cp] + px[1][cp] + px[2][cp] + px[3][cp];
        float sy = py[0][cp] + py[1][cp] + py[2][cp] + py[3][cp];
        partials[(size_t)blockIdx.x * 128 + cp * 2]     = sx;
        partials[(size_t)blockIdx.x * 128 + cp * 2 + 1] = sy;
    }
}

// ------------------------------------------------- pooling stage 2 + MLP head
__global__ __launch_bounds__(128) void head_kernel(const float* __restrict__ partials,
                                                   const int* __restrict__ batch,
                                                   const float* __restrict__ b4,
                                                   const float* __restrict__ Wd1,
                                                   const float* __restrict__ bd1,
                                                   const float* __restrict__ Wd2,
                                                   const float* __restrict__ bd2,
                                                   const float* __restrict__ Wo,
                                                   const float* __restrict__ bo,
                                                   float* __restrict__ out, int N) {
    int g = blockIdx.x;
    int j = threadIdx.x;
    __shared__ float sA[128], sB[128], red[128];
    int lo = 0, hi = N;
    while (lo < hi) { int m = (lo + hi) >> 1; if (batch[m] < g) lo = m + 1; else hi = m; }
    int beg = lo;
    lo = beg; hi = N;
    while (lo < hi) { int m = (lo + hi) >> 1; if (batch[m] < g + 1) lo = m + 1; else hi = m; }
    int cnt = lo - beg;
    float s = 0.f;
#pragma unroll
    for (int p = 0; p < 8; ++p) s += partials[(size_t)(g * 8 + p) * 128 + j];
    sA[j] = (cnt > 0) ? s / (float)cnt + b4[j] : 0.f;
    __syncthreads();
    float a = bd1[j];
#pragma unroll 4
    for (int k = 0; k < 128; ++k) a += sA[k] * Wd1[k * HIDDEN + j];
    sB[j] = fmaxf(a, 0.f);
    __syncthreads();
    a = bd2[j];
#pragma unroll 4
    for (int k = 0; k < 128; ++k) a += sB[k] * Wd2[k * HIDDEN + j];
    red[j] = fmaxf(a, 0.f) * Wo[j];
    __syncthreads();
    for (int d = 64; d > 0; d >>= 1) {
        if (j < d) red[j] += red[j + d];
        __syncthreads();
    }
    if (j == 0) out[g] = red[0] + bo[0];
}

// ============================================================================
extern "C" void kernel_launch(void* const* d_in, const int* in_sizes, int n_in,
                              void* d_out, int out_size, void* d_ws, size_t ws_size,
                              hipStream_t stream) {
    const float* x   = (const float*)d_in[0];
    const int*   ei  = (const int*)d_in[1];
    const int*   bat = (const int*)d_in[2];
    const float* W1  = (const float*)d_in[3];
    const float* b1  = (const float*)d_in[4];
    const float* W2  = (const float*)d_in[5];
    const float* b2  = (const float*)d_in[6];
    const float* W4  = (const float*)d_in[7];
    const float* b4  = (const float*)d_in[8];
    const float* Wd1 = (const float*)d_in[9];
    const float* bd1 = (const float*)d_in[10];
    const float* Wd2 = (const float*)d_in[11];
    const float* bd2 = (const float*)d_in[12];
    const float* Wo  = (const float*)d_in[13];
    const float* bo  = (const float*)d_in[14];
    float* out = (float*)d_out;

    const int N = in_sizes[0] / 11;
    const int E = in_sizes[1] / 2;
    const int* row = ei;
    const int* col = ei + E;
    const int B = (N + (1 << BSHIFT) - 1) >> BSHIFT;   // #buckets
    const int ngroups = (N + 15) / 16;

    size_t off = 0;
    auto carve = [&](size_t bytes) {
        void* p = (char*)d_ws + off;
        off += (bytes + 255) & ~(size_t)255;
        return p;
    };
    __half* bufHA    = (__half*)carve((size_t)N * HIDDEN * 2);
    __half* bufHB    = (__half*)carve((size_t)N * HIDDEN * 2);
    __half* xp       = (__half*)carve((size_t)N * 16 * 2);
    float*  aggx     = (float*)carve((size_t)N * 16 * 4);
    int*    offsets  = (int*)carve((size_t)(N + 1) * 4);
    float*  dinv     = (float*)carve((size_t)N * 4);
    int*    sorted_r = (int*)carve((size_t)E * 4);
    int*    bcnt     = (int*)carve((size_t)512 * 4);
    int*    bbase    = (int*)carve((size_t)512 * 4);
    float*  partials = (float*)carve((size_t)128 * 8 * 128 * 4);
    __half* packW2   = (__half*)carve((size_t)(32768 + 128) * 2);
    __half* packW4   = (__half*)carve((size_t)(32768 + 128) * 2);
    // ptmp aliases bufHA (dead until gemm_in_agg; B*BCAP*8 = 19.2 MB < 25.6 MB)
    int2* ptmp = (int2*)bufHA;
    (void)ws_size; (void)n_in; (void)out_size;

    // ---- build CSR: bucket-binned, no global histogram / scatter atomics
    hipMemsetAsync(bcnt, 0, (size_t)512 * 4, stream);
    fill_bin<<<(E + CHUNK - 1) / CHUNK, 256, 0, stream>>>(row, col, bcnt, ptmp, E);
    scan_buckets<<<1, 512, 0, stream>>>(bcnt, bbase, B);
    fill_scatter<<<B, 256, 0, stream>>>(ptmp, bcnt, bbase, offsets, dinv,
                                        sorted_r, N, E);

    // ---- pack weights for MFMA (independent of CSR)
    pack_w<<<8, 256, 0, stream>>>(W2, b1, packW2);
    pack_w<<<8, 256, 0, stream>>>(W4, b2, packW4);

    int aggBlocks = (N + 3) / 4;

    // ---- layer 1: aggregate dinv-folded fp16 input, then GEMM (linearity)
    pad_x<<<(N * 16 + 255) / 256, 256, 0, stream>>>(x, dinv, xp, N);
    agg16<<<aggBlocks, 256, 0, stream>>>(xp, aggx, offsets, sorted_r, dinv, N);
    gemm_in_agg<<<(N + 1) / 2, 256, 0, stream>>>(aggx, W1, bufHA, N);
    // ---- layer 2 (register-W MFMA GEMM: relu(h1+b1)@W2, dinv folded)
    gemm_mfma<<<1024, 256, 0, stream>>>(bufHA, packW2, dinv, bufHB, N, ngroups);
    agg128h<<<aggBlocks, 256, 0, stream>>>(bufHB, bufHA, offsets, sorted_r, dinv, N);
    // ---- layer 3
    gemm_mfma<<<1024, 256, 0, stream>>>(bufHA, packW4, dinv, bufHB, N, ngroups);
    agg128h<<<aggBlocks, 256, 0, stream>>>(bufHB, bufHA, offsets, sorted_r, dinv, N);
    // ---- pool + head
    pool_partial<<<128 * 8, 256, 0, stream>>>(bufHA, bat, partials, N);
    head_kernel<<<128, 128, 0, stream>>>(partials, bat, b4, Wd1, bd1, Wd2, bd2,
                                         Wo, bo, out, N);
}

// Round 12
// 310.369 us; speedup vs baseline: 1.8836x; 1.0750x over previous
//
#include <hip/hip_runtime.h>
#include <hip/hip_fp16.h>

#define HIDDEN 128
#define BSHIFT 8          // bucket = 256 destination nodes
#define BMASK 255
#define CHUNK 4096        // edges per fill_bin block (40 KB LDS -> 4 blocks/CU)
#define BCAP 6144         // per-bucket capacity in ptmp (mean 4096, 32 sigma)

typedef _Float16 h8 __attribute__((ext_vector_type(8)));
typedef float f4x __attribute__((ext_vector_type(4)));

// ----------------- fill pass 1: LDS-bin edges into bucket-strided temp array
__global__ __launch_bounds__(256) void fill_bin(const int* __restrict__ row,
                                                const int* __restrict__ col,
                                                int* __restrict__ bcnt,
                                                int2* __restrict__ ptmp, int E) {
    __shared__ int cnt[512], start[512], place[512], gbase[512];
    __shared__ int ssum[256];
    __shared__ int2 stage[CHUNK];
    int t = threadIdx.x;
    int e0 = blockIdx.x * CHUNK;
    int e1 = min(e0 + CHUNK, E);
    cnt[t] = 0; cnt[t + 256] = 0;
    __syncthreads();
    for (int e = e0 + t; e < e1; e += 256)
        atomicAdd(&cnt[col[e] >> BSHIFT], 1);
    __syncthreads();
    int s2 = cnt[2 * t] + cnt[2 * t + 1];
    ssum[t] = s2;
    __syncthreads();
    for (int d = 1; d < 256; d <<= 1) {
        int v = (t >= d) ? ssum[t - d] : 0;
        __syncthreads();
        ssum[t] += v;
        __syncthreads();
    }
    int excl = ssum[t] - s2;
    start[2 * t] = excl;
    start[2 * t + 1] = excl + cnt[2 * t];
    place[2 * t] = excl;
    place[2 * t + 1] = excl + cnt[2 * t];
    __syncthreads();
    for (int e = e0 + t; e < e1; e += 256) {
        int c = col[e], r = row[e];
        int slot = atomicAdd(&place[c >> BSHIFT], 1);
        stage[slot] = make_int2(r, c);
    }
    {
        int c0 = cnt[t], c1 = cnt[t + 256];
        if (c0 > 0) gbase[t] = atomicAdd(&bcnt[t], c0);
        if (c1 > 0) gbase[t + 256] = atomicAdd(&bcnt[t + 256], c1);
    }
    __syncthreads();
    int n = e1 - e0;
    for (int i = t; i < n; i += 256) {
        int2 p = stage[i];
        int b = p.y >> BSHIFT;
        ptmp[(size_t)b * BCAP + gbase[b] + (i - start[b])] = p;
    }
}

// --------------- tiny single-block scan of bucket totals -> global CSR bases
__global__ __launch_bounds__(512) void scan_buckets(const int* __restrict__ bcnt,
                                                    int* __restrict__ bbase, int NB) {
    __shared__ int s[512];
    int t = threadIdx.x;
    int v0 = (t < NB) ? bcnt[t] : 0;
    s[t] = v0;
    __syncthreads();
    for (int d = 1; d < 512; d <<= 1) {
        int v = (t >= d) ? s[t - d] : 0;
        __syncthreads();
        s[t] += v;
        __syncthreads();
    }
    bbase[t] = s[t] - v0;   // exclusive prefix
}

// ---- fill pass 2: one block per bucket — LDS degree histogram + local scatter
// also pads this bucket's x rows into dinv-folded fp16 xp (fused old pad_x)
__global__ __launch_bounds__(256) void fill_scatter(const int2* __restrict__ ptmp,
                                                    const int* __restrict__ bcnt,
                                                    const int* __restrict__ bbase,
                                                    const float* __restrict__ x,
                                                    int* __restrict__ offsets,
                                                    float* __restrict__ dinv,
                                                    int* __restrict__ sorted_r,
                                                    __half* __restrict__ xp,
                                                    int N, int E) {
    __shared__ int2 stage[BCAP];               // 48 KB
    __shared__ int cnt[256], loff[256], cur[256];
    int b = blockIdx.x, t = threadIdx.x;
    int m = bcnt[b];
    int base = bbase[b];
    int nbase = b << BSHIFT;
    cnt[t] = 0;
    __syncthreads();
    for (int i = t; i < m; i += 256) {
        int2 p = ptmp[(size_t)b * BCAP + i];
        stage[i] = p;
        atomicAdd(&cnt[p.y & BMASK], 1);
    }
    __syncthreads();
    int my = cnt[t];
    loff[t] = my;
    __syncthreads();
    for (int d = 1; d < 256; d <<= 1) {
        int v = (t >= d) ? loff[t - d] : 0;
        __syncthreads();
        loff[t] += v;
        __syncthreads();
    }
    int excl = loff[t] - my;
    cur[t] = excl;
    int node = nbase + t;
    float dv = rsqrtf((float)(my + 1));
    if (node < N) {
        offsets[node] = base + excl;
        dinv[node] = dv;
        // fused pad_x: xp[node] = fp16(x[node][0..10] * dinv[node]), pad to 16
        __half hrow[16];
#pragma unroll
        for (int c = 0; c < 11; ++c)
            hrow[c] = __float2half(x[(size_t)node * 11 + c] * dv);
#pragma unroll
        for (int c = 11; c < 16; ++c) hrow[c] = __float2half(0.f);
        *(uint4*)(xp + (size_t)node * 16)     = *(uint4*)hrow;
        *(uint4*)(xp + (size_t)node * 16 + 8) = *(uint4*)(hrow + 8);
    }
    if (b == gridDim.x - 1 && t == 0) offsets[N] = E;
    __syncthreads();
    for (int i = t; i < m; i += 256) {
        int2 p = stage[i];
        int slot = atomicAdd(&cur[p.y & BMASK], 1);
        sorted_r[base + slot] = p.x;   // contiguous ~16 KB region, block-local
    }
}

// ------ agg16 + input GEMM fused: bufHA[c] = fp16( (dc*(sum+self))[:11] @ W1 )
// 4 nodes/block (1 per wave); gather 2-deep batched; GEMM vs LDS-resident W1.
__global__ __launch_bounds__(256) void agg16_fused(const __half* __restrict__ xp,
                                                   const float* __restrict__ W1,
                                                   const int* __restrict__ offsets,
                                                   const int* __restrict__ sorted_r,
                                                   const float* __restrict__ dinv,
                                                   __half* __restrict__ out, int N) {
    __shared__ float W1s[11 * 128];   // 5.6 KB
    __shared__ float arow[4][16];
    int t = threadIdx.x;
    for (int q = t; q < 11 * 128; q += 256) W1s[q] = W1[q];
    int wv = t >> 6, lane = t & 63;
    int c = blockIdx.x * 4 + wv;
    bool valid = c < N;
    int g = lane >> 3, cp = lane & 7;
    const __half2* xp2 = (const __half2*)xp;
    float ax = 0.f, ay = 0.f;
    if (valid) {
        int beg = offsets[c], end = offsets[c + 1];
        if (g == 0) {
            float2 v = __half22float2(xp2[(size_t)c * 8 + cp]);   // self (dc folded)
            ax = v.x; ay = v.y;
        }
        int i = beg;
        for (; i + 16 <= end; i += 16) {
            int r0 = sorted_r[i + g];
            int r1 = sorted_r[i + g + 8];
            float2 v0 = __half22float2(xp2[(size_t)r0 * 8 + cp]);
            float2 v1 = __half22float2(xp2[(size_t)r1 * 8 + cp]);
            ax += v0.x + v1.x; ay += v0.y + v1.y;
        }
        if (i < end) {                       // predicated batch tail
            int last = end - 1;
            int i0 = i + g, i1 = i + g + 8;
            int r0 = sorted_r[min(i0, last)];
            int r1 = sorted_r[min(i1, last)];
            float2 v0 = __half22float2(xp2[(size_t)r0 * 8 + cp]);
            float2 v1 = __half22float2(xp2[(size_t)r1 * 8 + cp]);
            if (i0 <= last) { ax += v0.x; ay += v0.y; }
            if (i1 <= last) { ax += v1.x; ay += v1.y; }
        }
    }
    ax += __shfl_xor(ax, 32); ay += __shfl_xor(ay, 32);
    ax += __shfl_xor(ax, 16); ay += __shfl_xor(ay, 16);
    ax += __shfl_xor(ax, 8);  ay += __shfl_xor(ay, 8);
    if (valid && lane < 8) {
        float dc = dinv[c];
        arow[wv][cp * 2]     = ax * dc;
        arow[wv][cp * 2 + 1] = ay * dc;
    }
    __syncthreads();
    // block GEMM: 4 nodes x 128 ch, 2 outputs per thread
    int j = t & 127, half = t >> 7;
#pragma unroll
    for (int nn = 0; nn < 2; ++nn) {
        int n = half * 2 + nn;
        int node = blockIdx.x * 4 + n;
        if (node < N) {
            float acc = 0.f;
#pragma unroll
            for (int cc = 0; cc < 11; ++cc) acc += arow[n][cc] * W1s[cc * 128 + j];
            out[(size_t)node * HIDDEN + j] = __float2half(acc);
        }
    }
}

// ---------------- pack W [128][128] fp32 -> MFMA fragment order, hi|lo fp16
__global__ __launch_bounds__(256) void pack_w(const float* __restrict__ W,
                                              const float* __restrict__ bias,
                                              __half* __restrict__ packed) {
    int q = blockIdx.x * 256 + threadIdx.x;
    if (q < 2048) {
        int s = q >> 9, rem = q & 511, ct = rem >> 6, l = rem & 63;
        int b = l >> 4, n = l & 15;
        __half hi8[8], lo8[8];
#pragma unroll
        for (int i = 0; i < 8; ++i) {
            float w = W[(s * 32 + b * 8 + i) * HIDDEN + ct * 16 + n];
            __half h = __float2half(w);
            hi8[i] = h;
            lo8[i] = __float2half(w - __half2float(h));
        }
        *(uint4*)(packed + (size_t)q * 8)         = *(uint4*)hi8;
        *(uint4*)(packed + 16384 + (size_t)q * 8) = *(uint4*)lo8;
    }
    if (q < 128) packed[32768 + q] = __float2half(bias[q]);
}

// ---- MFMA GEMM, register-resident W (swapped operands, no LDS)
__global__ __launch_bounds__(256, 2) void gemm_mfma(const __half* __restrict__ H,
                                                    const __half* __restrict__ packed,
                                                    const float* __restrict__ dinv,
                                                    __half* __restrict__ out,
                                                    int N, int ngroups) {
    int l = threadIdx.x & 63, wv = threadIdx.x >> 6;
    int cthalf = wv & 1;
    int n16 = l & 15, koct = l >> 4;
    h8 whi[4][4], wlo[4][4];
#pragma unroll
    for (int s = 0; s < 4; ++s)
#pragma unroll
        for (int mt = 0; mt < 4; ++mt) {
            int ct = cthalf * 4 + mt;
            whi[s][mt] = *(const h8*)(packed + (size_t)((s * 8 + ct) * 64 + l) * 8);
            wlo[s][mt] = *(const h8*)(packed + 16384 + (size_t)((s * 8 + ct) * 64 + l) * 8);
        }
    h8 biasf[4];
    const __half* bias_h = packed + 32768;
#pragma unroll
    for (int s = 0; s < 4; ++s)
        biasf[s] = *(const h8*)(bias_h + s * 32 + koct * 8);

    for (int g = blockIdx.x * 2 + (wv >> 1); g < ngroups; g += gridDim.x * 2) {
        int node = g * 16 + n16;
        bool ok = node < N;
        f4x acc[4];
#pragma unroll
        for (int mt = 0; mt < 4; ++mt) acc[mt] = (f4x){0.f, 0.f, 0.f, 0.f};
#pragma unroll
        for (int s = 0; s < 4; ++s) {
            uint4 bv = make_uint4(0u, 0u, 0u, 0u);
            if (ok) bv = *(const uint4*)(H + (size_t)node * HIDDEN + s * 32 + koct * 8);
            __half2* bh2 = (__half2*)&bv;
            const __half2* bb = (const __half2*)&biasf[s];
#pragma unroll
            for (int p = 0; p < 4; ++p) {
                float2 f  = __half22float2(bh2[p]);
                float2 bf = __half22float2(bb[p]);
                bh2[p] = __floats2half2_rn(fmaxf(f.x + bf.x, 0.f), fmaxf(f.y + bf.y, 0.f));
            }
            h8 bfrag = *(h8*)&bv;
#pragma unroll
            for (int mt = 0; mt < 4; ++mt) {
                acc[mt] = __builtin_amdgcn_mfma_f32_16x16x32_f16(whi[s][mt], bfrag, acc[mt], 0, 0, 0);
                acc[mt] = __builtin_amdgcn_mfma_f32_16x16x32_f16(wlo[s][mt], bfrag, acc[mt], 0, 0, 0);
            }
        }
        if (ok) {
            float dv = dinv[node];
#pragma unroll
            for (int mt = 0; mt < 4; ++mt) {
                int ch = (cthalf * 4 + mt) * 16 + koct * 4;
                __half2 h01 = __floats2half2_rn(acc[mt][0] * dv, acc[mt][1] * dv);
                __half2 h23 = __floats2half2_rn(acc[mt][2] * dv, acc[mt][3] * dv);
                uint2 o;
                o.x = *(unsigned int*)&h01; o.y = *(unsigned int*)&h23;
                *(uint2*)(out + (size_t)node * HIDDEN + ch) = o;
            }
        }
    }
}

// -------- aggregation 128ch fp16; serial remainder replaced by predicated batch
__global__ __launch_bounds__(256) void agg128h(const __half* __restrict__ src,
                                               __half* __restrict__ dst,
                                               const int* __restrict__ offsets,
                                               const int* __restrict__ sorted_r,
                                               const float* __restrict__ dinv, int N) {
    int wid  = (blockIdx.x * 256 + threadIdx.x) >> 6;
    int lane = threadIdx.x & 63;
    if (wid >= N) return;
    int c = wid;
    int beg = offsets[c], end = offsets[c + 1];
    int g = lane >> 4, sub = lane & 15;
    const uint4* hp = (const uint4*)src;
    float a0=0.f,a1=0.f,a2=0.f,a3=0.f,a4=0.f,a5=0.f,a6=0.f,a7=0.f;

    auto accum = [&](uint4 u) {
        __half2 p0 = *(__half2*)&u.x, p1 = *(__half2*)&u.y;
        __half2 p2 = *(__half2*)&u.z, p3 = *(__half2*)&u.w;
        float2 f0 = __half22float2(p0), f1 = __half22float2(p1);
        float2 f2 = __half22float2(p2), f3 = __half22float2(p3);
        a0 += f0.x; a1 += f0.y; a2 += f1.x; a3 += f1.y;
        a4 += f2.x; a5 += f2.y; a6 += f3.x; a7 += f3.y;
    };

    if (g == 0) accum(hp[(size_t)c * 16 + sub]);   // self loop (dc folded)

    int i = beg;
    for (; i + 16 <= end; i += 16) {               // full 16-edge phases
        int base = i + 4 * g;
        int r0 = sorted_r[base + 0];
        int r1 = sorted_r[base + 1];
        int r2 = sorted_r[base + 2];
        int r3 = sorted_r[base + 3];
        uint4 u0 = hp[(size_t)r0 * 16 + sub];
        uint4 u1 = hp[(size_t)r1 * 16 + sub];
        uint4 u2 = hp[(size_t)r2 * 16 + sub];
        uint4 u3 = hp[(size_t)r3 * 16 + sub];
        accum(u0); accum(u1); accum(u2); accum(u3);
    }
    if (i < end) {                                 // predicated batch tail
        int last = end - 1;
        int i0 = i + 4 * g, i1 = i0 + 1, i2 = i0 + 2, i3 = i0 + 3;
        int r0 = sorted_r[min(i0, last)];
        int r1 = sorted_r[min(i1, last)];
        int r2 = sorted_r[min(i2, last)];
        int r3 = sorted_r[min(i3, last)];
        uint4 u0 = hp[(size_t)r0 * 16 + sub];
        uint4 u1 = hp[(size_t)r1 * 16 + sub];
        uint4 u2 = hp[(size_t)r2 * 16 + sub];
        uint4 u3 = hp[(size_t)r3 * 16 + sub];
        if (i0 <= last) accum(u0);
        if (i1 <= last) accum(u1);
        if (i2 <= last) accum(u2);
        if (i3 <= last) accum(u3);
    }
    a0 += __shfl_xor(a0, 32); a1 += __shfl_xor(a1, 32);
    a2 += __shfl_xor(a2, 32); a3 += __shfl_xor(a3, 32);
    a4 += __shfl_xor(a4, 32); a5 += __shfl_xor(a5, 32);
    a6 += __shfl_xor(a6, 32); a7 += __shfl_xor(a7, 32);
    a0 += __shfl_xor(a0, 16); a1 += __shfl_xor(a1, 16);
    a2 += __shfl_xor(a2, 16); a3 += __shfl_xor(a3, 16);
    a4 += __shfl_xor(a4, 16); a5 += __shfl_xor(a5, 16);
    a6 += __shfl_xor(a6, 16); a7 += __shfl_xor(a7, 16);
    if (g == 0) {
        float dc = dinv[c];
        __half2 h01 = __floats2half2_rn(a0 * dc, a1 * dc);
        __half2 h23 = __floats2half2_rn(a2 * dc, a3 * dc);
        __half2 h45 = __floats2half2_rn(a4 * dc, a5 * dc);
        __half2 h67 = __floats2half2_rn(a6 * dc, a7 * dc);
        uint4 o;
        o.x = *(unsigned int*)&h01; o.y = *(unsigned int*)&h23;
        o.z = *(unsigned int*)&h45; o.w = *(unsigned int*)&h67;
        ((uint4*)dst)[(size_t)c * 16 + sub] = o;
    }
}

// --------------------------------------------- pooling stage 1: partial sums
__global__ __launch_bounds__(256) void pool_partial(const __half* __restrict__ h,
                                                    const int* __restrict__ batch,
                                                    float* __restrict__ partials, int N) {
    int g = blockIdx.x >> 3, part8 = blockIdx.x & 7;
    int t = threadIdx.x, cp = t & 63, rp = t >> 6;
    int lo = 0, hi = N;
    while (lo < hi) { int m = (lo + hi) >> 1; if (batch[m] < g) lo = m + 1; else hi = m; }
    int beg = lo;
    lo = beg; hi = N;
    while (lo < hi) { int m = (lo + hi) >> 1; if (batch[m] < g + 1) lo = m + 1; else hi = m; }
    int end = lo;
    const __half2* h2 = (const __half2*)h;
    float ax = 0.f, ay = 0.f;
    for (int i = beg + part8 * 4 + rp; i < end; i += 32) {
        float2 v = __half22float2(h2[(size_t)i * 64 + cp]);
        ax += v.x; ay += v.y;
    }
    __shared__ float px[4][64], py[4][64];
    px[rp][cp] = ax; py[rp][cp] = ay;
    __syncthreads();
    if (rp == 0) {
        float sx = px[0][cp] + px[1][cp] + px[2][cp] + px[3][cp];
        float sy = py[0][cp] + py[1][cp] + py[2][cp] + py[3][cp];
        partials[(size_t)blockIdx.x * 128 + cp * 2]     = sx;
        partials[(size_t)blockIdx.x * 128 + cp * 2 + 1] = sy;
    }
}

// ------------------------------------------------- pooling stage 2 + MLP head
__global__ __launch_bounds__(128) void head_kernel(const float* __restrict__ partials,
                                                   const int* __restrict__ batch,
                                                   const float* __restrict__ b4,
                                                   const float* __restrict__ Wd1,
                                                   const float* __restrict__ bd1,
                                                   const float* __restrict__ Wd2,
                                                   const float* __restrict__ bd2,
                                                   const float* __restrict__ Wo,
                                                   const float* __restrict__ bo,
                                                   float* __restrict__ out, int N) {
    int g = blockIdx.x;
    int j = threadIdx.x;
    __shared__ float sA[128], sB[128], red[128];
    int lo = 0, hi = N;
    while (lo < hi) { int m = (lo + hi) >> 1; if (batch[m] < g) lo = m + 1; else hi = m; }
    int beg = lo;
    lo = beg; hi = N;
    while (lo < hi) { int m = (lo + hi) >> 1; if (batch[m] < g + 1) lo = m + 1; else hi = m; }
    int cnt = lo - beg;
    float s = 0.f;
#pragma unroll
    for (int p = 0; p < 8; ++p) s += partials[(size_t)(g * 8 + p) * 128 + j];
    sA[j] = (cnt > 0) ? s / (float)cnt + b4[j] : 0.f;
    __syncthreads();
    float a = bd1[j];
#pragma unroll 4
    for (int k = 0; k < 128; ++k) a += sA[k] * Wd1[k * HIDDEN + j];
    sB[j] = fmaxf(a, 0.f);
    __syncthreads();
    a = bd2[j];
#pragma unroll 4
    for (int k = 0; k < 128; ++k) a += sB[k] * Wd2[k * HIDDEN + j];
    red[j] = fmaxf(a, 0.f) * Wo[j];
    __syncthreads();
    for (int d = 64; d > 0; d >>= 1) {
        if (j < d) red[j] += red[j + d];
        __syncthreads();
    }
    if (j == 0) out[g] = red[0] + bo[0];
}

// ============================================================================
extern "C" void kernel_launch(void* const* d_in, const int* in_sizes, int n_in,
                              void* d_out, int out_size, void* d_ws, size_t ws_size,
                              hipStream_t stream) {
    const float* x   = (const float*)d_in[0];
    const int*   ei  = (const int*)d_in[1];
    const int*   bat = (const int*)d_in[2];
    const float* W1  = (const float*)d_in[3];
    const float* b1  = (const float*)d_in[4];
    const float* W2  = (const float*)d_in[5];
    const float* b2  = (const float*)d_in[6];
    const float* W4  = (const float*)d_in[7];
    const float* b4  = (const float*)d_in[8];
    const float* Wd1 = (const float*)d_in[9];
    const float* bd1 = (const float*)d_in[10];
    const float* Wd2 = (const float*)d_in[11];
    const float* bd2 = (const float*)d_in[12];
    const float* Wo  = (const float*)d_in[13];
    const float* bo  = (const float*)d_in[14];
    float* out = (float*)d_out;

    const int N = in_sizes[0] / 11;
    const int E = in_sizes[1] / 2;
    const int* row = ei;
    const int* col = ei + E;
    const int B = (N + (1 << BSHIFT) - 1) >> BSHIFT;   // #buckets
    const int ngroups = (N + 15) / 16;

    size_t off = 0;
    auto carve = [&](size_t bytes) {
        void* p = (char*)d_ws + off;
        off += (bytes + 255) & ~(size_t)255;
        return p;
    };
    __half* bufHA    = (__half*)carve((size_t)N * HIDDEN * 2);
    __half* bufHB    = (__half*)carve((size_t)N * HIDDEN * 2);
    __half* xp       = (__half*)carve((size_t)N * 16 * 2);
    int*    offsets  = (int*)carve((size_t)(N + 1) * 4);
    float*  dinv     = (float*)carve((size_t)N * 4);
    int*    sorted_r = (int*)carve((size_t)E * 4);
    int*    bcnt     = (int*)carve((size_t)512 * 4);
    int*    bbase    = (int*)carve((size_t)512 * 4);
    float*  partials = (float*)carve((size_t)128 * 8 * 128 * 4);
    __half* packW2   = (__half*)carve((size_t)(32768 + 128) * 2);
    __half* packW4   = (__half*)carve((size_t)(32768 + 128) * 2);
    // ptmp aliases bufHA (dead until agg16_fused; B*BCAP*8 = 19.2 MB < 25.6 MB)
    int2* ptmp = (int2*)bufHA;
    (void)ws_size; (void)n_in; (void)out_size;

    // ---- build CSR (+ fused xp padding): bucket-binned, no global histogram
    hipMemsetAsync(bcnt, 0, (size_t)512 * 4, stream);
    fill_bin<<<(E + CHUNK - 1) / CHUNK, 256, 0, stream>>>(row, col, bcnt, ptmp, E);
    scan_buckets<<<1, 512, 0, stream>>>(bcnt, bbase, B);
    fill_scatter<<<B, 256, 0, stream>>>(ptmp, bcnt, bbase, x, offsets, dinv,
                                        sorted_r, xp, N, E);

    // ---- pack weights for MFMA (independent of CSR)
    pack_w<<<8, 256, 0, stream>>>(W2, b1, packW2);
    pack_w<<<8, 256, 0, stream>>>(W4, b2, packW4);

    int aggBlocks = (N + 3) / 4;

    // ---- layer 1: fused aggregate+GEMM (agg is linear; dinv folded in xp)
    agg16_fused<<<aggBlocks, 256, 0, stream>>>(xp, W1, offsets, sorted_r, dinv,
                                               bufHA, N);
    // ---- layer 2 (register-W MFMA GEMM: relu(h1+b1)@W2, dinv folded)
    gemm_mfma<<<1024, 256, 0, stream>>>(bufHA, packW2, dinv, bufHB, N, ngroups);
    agg128h<<<aggBlocks, 256, 0, stream>>>(bufHB, bufHA, offsets, sorted_r, dinv, N);
    // ---- layer 3
    gemm_mfma<<<1024, 256, 0, stream>>>(bufHA, packW4, dinv, bufHB, N, ngroups);
    agg128h<<<aggBlocks, 256, 0, stream>>>(bufHB, bufHA, offsets, sorted_r, dinv, N);
    // ---- pool + head
    pool_partial<<<128 * 8, 256, 0, stream>>>(bufHA, bat, partials, N);
    head_kernel<<<128, 128, 0, stream>>>(partials, bat, b4, Wd1, bd1, Wd2, bd2,
                                         Wo, bo, out, N);
}